// Round 4
// baseline (969.460 us; speedup 1.0000x reference)
//
#include <hip/hip_runtime.h>

typedef unsigned short u16;
typedef short bf16x8 __attribute__((ext_vector_type(8)));
typedef float f32x4 __attribute__((ext_vector_type(4)));
typedef u16 u16x8 __attribute__((ext_vector_type(8)));
typedef unsigned u32x4 __attribute__((ext_vector_type(4)));

__device__ __forceinline__ float b2f(u16 v) {
  union { unsigned u; float f; } x; x.u = ((unsigned)v) << 16; return x.f;
}
__device__ __forceinline__ u16 f2b(float f) {
  unsigned u = __float_as_uint(f);
  unsigned r = (u + 0x7FFFu + ((u >> 16) & 1u)) >> 16;
  return (u16)r;
}
// dtype-agnostic input read: bf==1 -> bf16, bf==0 -> f32
__device__ __forceinline__ float rin(const void* p, size_t i, int bf) {
  return bf ? b2f(((const u16*)p)[i]) : ((const float*)p)[i];
}

// ---- detect input dtype from w0's bit patterns (low u16 of each u32 word) ----
__global__ void detect_kernel(const unsigned* __restrict__ w0, int* __restrict__ flag) {
  if (threadIdx.x == 0) {
    int ok = 1;
    for (int i = 0; i < 64; ++i) {
      unsigned lo = w0[i] & 0xFFFFu;
      unsigned e = (lo >> 7) & 0xFFu;   // bf16 biased exponent if data is bf16
      if (e < 100u || e > 126u) { ok = 0; break; }
    }
    flag[0] = ok;   // 1 = bf16 inputs/outputs, 0 = f32 inputs/outputs
  }
}

// ---------------- styles: s[b,i] = sum_z w[b,z]*sW[i,z] + sB[i] ----------------
__global__ void style_kernel(const void* __restrict__ w, const void* __restrict__ sW,
                             const void* __restrict__ sB, float* __restrict__ out,
                             const int* __restrict__ flag) {
  const int bf = flag[0];
  __shared__ float wl[512];
  const int b = blockIdx.x, tid = threadIdx.x;
  for (int e = tid; e < 512; e += 256) wl[e] = rin(w, b * 512 + e, bf);
  __syncthreads();
  for (int i = tid; i < 512; i += 256) {
    float acc = 0.f;
    for (int z = 0; z < 512; ++z) acc += wl[z] * rin(sW, (size_t)i * 512 + z, bf);
    out[b * 512 + i] = acc + rin(sB, i, bf);
  }
}

// ---- demod d[b,o] = rsqrt(sum_i (sum_t W[o,i,t]^2) * s[b,i]^2 + eps); repack W -> Wp[t][o][i]
__global__ void demod_kernel(const void* __restrict__ W, const float* __restrict__ s,
                             float* __restrict__ d, u16* __restrict__ Wp,
                             const int* __restrict__ flag) {
  const int bf = flag[0];
  const int o = blockIdx.x, tid = threadIdx.x;
  __shared__ float wsq[512];
  __shared__ float red[256];
  for (int i = tid; i < 512; i += 256) {
    float ss = 0.f;
#pragma unroll
    for (int t = 0; t < 9; ++t) {
      const float f = rin(W, (size_t)(o * 512 + i) * 9 + t, bf);
      ss += f * f;
      Wp[t * 262144 + o * 512 + i] = f2b(f);
    }
    wsq[i] = ss;
  }
  __syncthreads();
  for (int b = 0; b < 8; ++b) {
    float part = 0.f;
    for (int i = tid; i < 512; i += 256) { float sv = s[b * 512 + i]; part += wsq[i] * sv * sv; }
    red[tid] = part; __syncthreads();
    for (int st = 128; st > 0; st >>= 1) { if (tid < st) red[tid] += red[tid + st]; __syncthreads(); }
    if (tid == 0) d[b * 512 + o] = rsqrtf(red[0] + 1e-8f);
    __syncthreads();
  }
}

// ---- bilinear 2x upsample * s0 -> bf16 NHWC scratch [bl][4096][512] inside d_out x-region
__global__ void upsample_kernel(const void* __restrict__ maps, const float* __restrict__ s,
                                void* __restrict__ outb, int b_base,
                                const int* __restrict__ flag) {
  const int bf = flag[0];
  const size_t esz = bf ? 2 : 4;
  u16* xg = (u16*)((char*)outb + (98304 + (size_t)(b_base >> 2) * 8388608) * esz);
  const int oy = blockIdx.x;       // 0..63
  const int i0 = blockIdx.y * 32;  // channel chunk
  const int bl = blockIdx.z;       // local batch 0..3
  const int bg = b_base + bl;
  const int tid = threadIdx.x;
  __shared__ float it[32][2][33];
  const int m = oy >> 1;
  int iy0, iy1; float wy0, wy1;
  if ((oy & 1) == 0) { iy0 = (m > 0) ? m - 1 : 0; iy1 = m; wy0 = 0.25f; wy1 = 0.75f; }
  else               { iy0 = m; iy1 = (m < 31) ? m + 1 : 31; wy0 = 0.75f; wy1 = 0.25f; }
#pragma unroll
  for (int k = 0; k < 8; ++k) {
    const int e = tid + k * 256;  // 32c x 2rows x 32x = 2048
    const int c = e >> 6, wsel = (e >> 5) & 1, x = e & 31;
    const int iy = wsel ? iy1 : iy0;
    it[c][wsel][x] = rin(maps, ((size_t)(bg * 512 + i0 + c) * 32 + iy) * 32 + x, bf);
  }
  __syncthreads();
#pragma unroll
  for (int k = 0; k < 8; ++k) {
    const int e = tid + k * 256;  // 64 xx * 32 c = 2048
    const int xx = e >> 5, c = e & 31;
    const int mx = xx >> 1;
    int ix0, ix1; float wx0, wx1;
    if ((xx & 1) == 0) { ix0 = (mx > 0) ? mx - 1 : 0; ix1 = mx; wx0 = 0.25f; wx1 = 0.75f; }
    else               { ix0 = mx; ix1 = (mx < 31) ? mx + 1 : 31; wx0 = 0.75f; wx1 = 0.25f; }
    const float r0 = wx0 * it[c][0][ix0] + wx1 * it[c][0][ix1];
    const float r1 = wx0 * it[c][1][ix0] + wx1 * it[c][1][ix1];
    const float v = (wy0 * r0 + wy1 * r1) * s[bg * 512 + i0 + c];
    xg[((size_t)(bl * 4096) + oy * 64 + xx) * 512 + i0 + c] = f2b(v);
  }
}

__global__ void zero_kernel(u32x4* __restrict__ p, int n16) {
  const int i = blockIdx.x * 256 + threadIdx.x;
  if (i < n16) { u32x4 z = {0, 0, 0, 0}; p[i] = z; }
}

// ---- conv0: implicit GEMM 3x3 over no-halo NHWC scratch (masked staging).
// epilogue: lrelu(acc*dm + b + ns*noise)*s1 -> actB halo NHWC [bl][66][66][512]
__global__ __launch_bounds__(256) void conv0_kernel(
    const void* __restrict__ outb, const u16* __restrict__ Wp,
    const float* __restrict__ dmod, const void* __restrict__ bias,
    const void* __restrict__ nsc, const void* __restrict__ noise,
    const float* __restrict__ snext, u16* __restrict__ actB, int b_base,
    const int* __restrict__ flag) {
  const int bf = flag[0];
  const size_t esz = bf ? 2 : 4;
  const u16* xg = (const u16*)((const char*)outb + (98304 + (size_t)(b_base >> 2) * 8388608) * esz);
  __shared__ __attribute__((aligned(16))) u16 Alds[4096];
  __shared__ __attribute__((aligned(16))) u16 Blds[4096];
  const int tid = threadIdx.x, lane = tid & 63, w = tid >> 6;
  const int wm = w >> 1, wn = w & 1;
  const int n0 = blockIdx.x * 128, o0 = blockIdx.y * 128;
  const int bl = blockIdx.z, bg = b_base + bl;

  const int srow = w * 32 + (lane >> 2);
  const int scol = (lane & 3) * 8;
  const size_t aA = (size_t)(o0 + srow) * 512 + scol;
  const int p0 = n0 + srow, p1 = p0 + 16;
  const int oy0 = p0 >> 6, ox0 = p0 & 63;
  const int oy1 = p1 >> 6, ox1 = p1 & 63;
  const int sidx = w * 1024 + lane * 8;

  f32x4 acc[4][4] = {};
  const int q = lane >> 4, mrow = lane & 15;

#pragma unroll 1
  for (int t = 0; t < 9; ++t) {
    const int ty = t / 3, tx = t % 3;
    const size_t wbase = (size_t)t * 262144;
    const int iy0 = oy0 + ty - 1, ix0 = ox0 + tx - 1;
    const int iy1 = oy1 + ty - 1, ix1 = ox1 + tx - 1;
    const bool ok0 = ((unsigned)iy0 < 64u) && ((unsigned)ix0 < 64u);
    const bool ok1 = ((unsigned)iy1 < 64u) && ((unsigned)ix1 < 64u);
    const size_t aB0 = ok0 ? (((size_t)(bl * 4096) + iy0 * 64 + ix0) * 512 + scol) : 0;
    const size_t aB1 = ok1 ? (((size_t)(bl * 4096) + iy1 * 64 + ix1) * 512 + scol) : 0;
#pragma unroll 1
    for (int kc = 0; kc < 16; ++kc) {
      const int ko = kc * 32;
      const u16x8 ra0 = *(const u16x8*)(Wp + wbase + aA + ko);
      const u16x8 ra1 = *(const u16x8*)(Wp + wbase + aA + ko + 16 * 512);
      u16x8 rb0 = {0, 0, 0, 0, 0, 0, 0, 0}, rb1 = {0, 0, 0, 0, 0, 0, 0, 0};
      if (ok0) rb0 = *(const u16x8*)(xg + aB0 + ko);
      if (ok1) rb1 = *(const u16x8*)(xg + aB1 + ko);
      __syncthreads();
      *(u16x8*)&Alds[sidx]       = ra0;
      *(u16x8*)&Alds[sidx + 512] = ra1;
      *(u16x8*)&Blds[sidx]       = rb0;
      *(u16x8*)&Blds[sidx + 512] = rb1;
      __syncthreads();
      bf16x8 af[4], bfv[4];
#pragma unroll
      for (int mi = 0; mi < 4; ++mi)
        af[mi] = *(const bf16x8*)&Alds[(wm * 64 + mi * 16 + mrow) * 32 + q * 8];
#pragma unroll
      for (int ni = 0; ni < 4; ++ni)
        bfv[ni] = *(const bf16x8*)&Blds[(wn * 64 + ni * 16 + mrow) * 32 + q * 8];
#pragma unroll
      for (int mi = 0; mi < 4; ++mi)
#pragma unroll
        for (int ni = 0; ni < 4; ++ni)
          acc[mi][ni] = __builtin_amdgcn_mfma_f32_16x16x32_bf16(af[mi], bfv[ni], acc[mi][ni], 0, 0, 0);
    }
  }

#pragma unroll
  for (int mi = 0; mi < 4; ++mi) {
    const int o = o0 + wm * 64 + mi * 16 + q * 4;
    const f32x4 dv = *(const f32x4*)&dmod[bg * 512 + o];
    const f32x4 sv = *(const f32x4*)&snext[bg * 512 + o];
    float bv[4], nv[4];
#pragma unroll
    for (int r = 0; r < 4; ++r) { bv[r] = rin(bias, o + r, bf); nv[r] = rin(nsc, o + r, bf); }
#pragma unroll
    for (int ni = 0; ni < 4; ++ni) {
      const int p = n0 + wn * 64 + ni * 16 + mrow;
      const float np = rin(noise, (size_t)bg * 4096 + p, bf);
      u16 pack[4];
#pragma unroll
      for (int r = 0; r < 4; ++r) {
        float v = acc[mi][ni][r] * dv[r] + bv[r] + nv[r] * np;
        v = (v >= 0.f) ? v : 0.2f * v;
        pack[r] = f2b(v * sv[r]);
      }
      const int oy = p >> 6, ox = p & 63;
      u16* dst = &actB[((size_t)(bl * 4356) + (oy + 1) * 66 + (ox + 1)) * 512 + o];
      dst[0] = pack[0]; dst[1] = pack[1]; dst[2] = pack[2]; dst[3] = pack[3];
    }
  }
}

// ---- conv1: implicit GEMM 3x3 over halo NHWC actB.
// epilogue: x = lrelu(acc*dm + b + ns*noise) -> d_out x-region (dual dtype, NCHW);
//           rgb partials: atomicAdd rgbacc[b][c][p] += sum_o rgbW[c][o]*(x*sR)[o]
__global__ __launch_bounds__(256) void conv1_kernel(
    const u16* __restrict__ actB, const u16* __restrict__ Wp,
    const float* __restrict__ dmod, const void* __restrict__ bias,
    const void* __restrict__ nsc, const void* __restrict__ noise,
    const float* __restrict__ sR, const void* __restrict__ rgbW,
    float* __restrict__ rgbacc, void* __restrict__ outb, int b_base,
    const int* __restrict__ flag) {
  const int bf = flag[0];
  __shared__ __attribute__((aligned(16))) u16 Alds[4096];
  __shared__ __attribute__((aligned(16))) u16 Blds[4096];
  __shared__ float rgbWl[1536];
  const int tid = threadIdx.x, lane = tid & 63, w = tid >> 6;
  const int wm = w >> 1, wn = w & 1;
  const int n0 = blockIdx.x * 128, o0 = blockIdx.y * 128;
  const int bl = blockIdx.z, bg = b_base + bl;

  for (int e = tid; e < 1536; e += 256) rgbWl[e] = rin(rgbW, e, bf);

  const int srow = w * 32 + (lane >> 2);
  const int scol = (lane & 3) * 8;
  const size_t aA = (size_t)(o0 + srow) * 512 + scol;
  const int p0 = n0 + srow, p1 = p0 + 16;
  const size_t aB0 = ((size_t)(bl * 4356) + (p0 >> 6) * 66 + (p0 & 63)) * 512 + scol;
  const size_t aB1 = ((size_t)(bl * 4356) + (p1 >> 6) * 66 + (p1 & 63)) * 512 + scol;
  const int sidx = w * 1024 + lane * 8;

  f32x4 acc[4][4] = {};
  const int q = lane >> 4, mrow = lane & 15;

#pragma unroll 1
  for (int t = 0; t < 9; ++t) {
    const int toffB = ((t / 3) * 66 + (t % 3)) * 512;
    const size_t wbase = (size_t)t * 262144;
#pragma unroll 1
    for (int kc = 0; kc < 16; ++kc) {
      const int ko = kc * 32;
      const u16x8 ra0 = *(const u16x8*)(Wp + wbase + aA + ko);
      const u16x8 ra1 = *(const u16x8*)(Wp + wbase + aA + ko + 16 * 512);
      const u16x8 rb0 = *(const u16x8*)(actB + aB0 + toffB + ko);
      const u16x8 rb1 = *(const u16x8*)(actB + aB1 + toffB + ko);
      __syncthreads();
      *(u16x8*)&Alds[sidx]       = ra0;
      *(u16x8*)&Alds[sidx + 512] = ra1;
      *(u16x8*)&Blds[sidx]       = rb0;
      *(u16x8*)&Blds[sidx + 512] = rb1;
      __syncthreads();
      bf16x8 af[4], bfv[4];
#pragma unroll
      for (int mi = 0; mi < 4; ++mi)
        af[mi] = *(const bf16x8*)&Alds[(wm * 64 + mi * 16 + mrow) * 32 + q * 8];
#pragma unroll
      for (int ni = 0; ni < 4; ++ni)
        bfv[ni] = *(const bf16x8*)&Blds[(wn * 64 + ni * 16 + mrow) * 32 + q * 8];
#pragma unroll
      for (int mi = 0; mi < 4; ++mi)
#pragma unroll
        for (int ni = 0; ni < 4; ++ni)
          acc[mi][ni] = __builtin_amdgcn_mfma_f32_16x16x32_bf16(af[mi], bfv[ni], acc[mi][ni], 0, 0, 0);
    }
  }

  const size_t esz = bf ? 2 : 4;
  char* xreg = (char*)outb + 98304 * esz;
  float racc[4][3] = {};
#pragma unroll
  for (int mi = 0; mi < 4; ++mi) {
    const int o = o0 + wm * 64 + mi * 16 + q * 4;
    const f32x4 dv = *(const f32x4*)&dmod[bg * 512 + o];
    const f32x4 srv = *(const f32x4*)&sR[bg * 512 + o];
    float bv[4], nv[4], w0l[4], w1l[4], w2l[4];
#pragma unroll
    for (int r = 0; r < 4; ++r) {
      bv[r] = rin(bias, o + r, bf); nv[r] = rin(nsc, o + r, bf);
      w0l[r] = rgbWl[o + r]; w1l[r] = rgbWl[512 + o + r]; w2l[r] = rgbWl[1024 + o + r];
    }
#pragma unroll
    for (int ni = 0; ni < 4; ++ni) {
      const int p = n0 + wn * 64 + ni * 16 + mrow;
      const float np = rin(noise, (size_t)bg * 4096 + p, bf);
#pragma unroll
      for (int r = 0; r < 4; ++r) {
        float v = acc[mi][ni][r] * dv[r] + bv[r] + nv[r] * np;
        v = (v >= 0.f) ? v : 0.2f * v;
        const size_t xi = (size_t)(bg * 512 + o + r) * 4096 + p;
        if (bf) ((u16*)xreg)[xi] = f2b(v); else ((float*)xreg)[xi] = v;
        const float xr = v * srv[r];
        racc[ni][0] += w0l[r] * xr;
        racc[ni][1] += w1l[r] * xr;
        racc[ni][2] += w2l[r] * xr;
      }
    }
  }
#pragma unroll
  for (int ni = 0; ni < 4; ++ni) {
    const int p = n0 + wn * 64 + ni * 16 + mrow;
#pragma unroll
    for (int c = 0; c < 3; ++c) {
      float t = racc[ni][c];
      t += __shfl_xor(t, 16, 64);
      t += __shfl_xor(t, 32, 64);
      if (lane < 16) atomicAdd(&rgbacc[(size_t)(bg * 3 + c) * 4096 + p], t);
    }
  }
}

// ---- finalize rgb: out[b,c,p] = up2(rgb) + rgbB[c] + rgbacc[b,c,p]
__global__ void rgbfin_kernel(const float* __restrict__ rgbacc, const void* __restrict__ rgbB,
                              const void* __restrict__ rgb, void* __restrict__ outb,
                              const int* __restrict__ flag) {
  const int bf = flag[0];
  const int g = blockIdx.x * 256 + threadIdx.x;  // 0..32767
  const int b = g >> 12, p = g & 4095;
  const int oy = p >> 6, ox = p & 63;
  const int m = oy >> 1; int iy0, iy1; float wy0, wy1;
  if ((oy & 1) == 0) { iy0 = (m > 0) ? m - 1 : 0; iy1 = m; wy0 = 0.25f; wy1 = 0.75f; }
  else               { iy0 = m; iy1 = (m < 31) ? m + 1 : 31; wy0 = 0.75f; wy1 = 0.25f; }
  const int mx = ox >> 1; int ix0, ix1; float wx0, wx1;
  if ((ox & 1) == 0) { ix0 = (mx > 0) ? mx - 1 : 0; ix1 = mx; wx0 = 0.25f; wx1 = 0.75f; }
  else               { ix0 = mx; ix1 = (mx < 31) ? mx + 1 : 31; wx0 = 0.75f; wx1 = 0.25f; }
#pragma unroll
  for (int c = 0; c < 3; ++c) {
    const size_t rb = (size_t)(b * 3 + c) * 1024;
    const float up = wy0 * (wx0 * rin(rgb, rb + iy0 * 32 + ix0, bf) + wx1 * rin(rgb, rb + iy0 * 32 + ix1, bf))
                   + wy1 * (wx0 * rin(rgb, rb + iy1 * 32 + ix0, bf) + wx1 * rin(rgb, rb + iy1 * 32 + ix1, bf));
    const float v = up + rin(rgbB, c, bf) + rgbacc[(size_t)(b * 3 + c) * 4096 + p];
    const size_t oi = ((size_t)(b * 3 + c) << 12) + p;
    if (bf) ((u16*)outb)[oi] = f2b(v); else ((float*)outb)[oi] = v;
  }
}

// ---------------- workspace layout (bytes), total ~26.5 MB ----------------
// flag:0(64)  s0:1024  s1:17408  sR:33792  dm0:50176  dm1:66560
// rgbacc:82944 (393216)
// Wp0:476160 (4718592)  Wp1:5194752 (4718592)
// actB:9913344 (17842176) -> end 27755520

extern "C" void kernel_launch(void* const* d_in, const int* in_sizes, int n_in,
                              void* d_out, int out_size, void* d_ws, size_t ws_size,
                              hipStream_t stream) {
  const void* maps   = d_in[0];
  const void* wlat   = d_in[1];
  const void* rgb    = d_in[2];
  const void* noise0 = d_in[3];
  const void* noise1 = d_in[4];
  const void* w0     = d_in[5];
  const void* b0     = d_in[6];
  const void* sW0    = d_in[7];
  const void* sB0    = d_in[8];
  const void* ns0    = d_in[9];
  const void* w1     = d_in[10];
  const void* b1     = d_in[11];
  const void* sW1    = d_in[12];
  const void* sB1    = d_in[13];
  const void* ns1    = d_in[14];
  const void* rgbW   = d_in[15];
  const void* rgbB   = d_in[16];
  const void* rgbSW  = d_in[17];
  const void* rgbSB  = d_in[18];

  char* ws = (char*)d_ws;
  int*   flg    = (int*)(ws + 0);
  float* s0     = (float*)(ws + 1024);
  float* s1     = (float*)(ws + 17408);
  float* sR     = (float*)(ws + 33792);
  float* dm0    = (float*)(ws + 50176);
  float* dm1    = (float*)(ws + 66560);
  float* rgbacc = (float*)(ws + 82944);
  u16*   Wp0    = (u16*)(ws + 476160);
  u16*   Wp1    = (u16*)(ws + 5194752);
  u16*   actB   = (u16*)(ws + 9913344);

  detect_kernel<<<1, 64, 0, stream>>>((const unsigned*)w0, flg);
  style_kernel<<<8, 256, 0, stream>>>(wlat, sW0, sB0, s0, flg);
  style_kernel<<<8, 256, 0, stream>>>(wlat, sW1, sB1, s1, flg);
  style_kernel<<<8, 256, 0, stream>>>(wlat, rgbSW, rgbSB, sR, flg);
  demod_kernel<<<512, 256, 0, stream>>>(w0, s0, dm0, Wp0, flg);
  demod_kernel<<<512, 256, 0, stream>>>(w1, s1, dm1, Wp1, flg);
  zero_kernel<<<96, 256, 0, stream>>>((u32x4*)rgbacc, 24576);

  for (int half = 0; half < 2; ++half) {
    const int b_base = half * 4;
    upsample_kernel<<<dim3(64, 16, 4), 256, 0, stream>>>(maps, s0, d_out, b_base, flg);
    zero_kernel<<<4356, 256, 0, stream>>>((u32x4*)actB, 1115136);
    conv0_kernel<<<dim3(32, 4, 4), 256, 0, stream>>>(d_out, Wp0, dm0, b0, ns0, noise0, s1,
                                                     actB, b_base, flg);
    conv1_kernel<<<dim3(32, 4, 4), 256, 0, stream>>>(actB, Wp1, dm1, b1, ns1, noise1, sR,
                                                     rgbW, rgbacc, d_out, b_base, flg);
  }
  rgbfin_kernel<<<128, 256, 0, stream>>>(rgbacc, rgbB, rgb, d_out, flg);
}

// Round 5
// 592.924 us; speedup vs baseline: 1.6351x; 1.6351x over previous
//
#include <hip/hip_runtime.h>

typedef unsigned short u16;
typedef short bf16x8 __attribute__((ext_vector_type(8)));
typedef float f32x4 __attribute__((ext_vector_type(4)));
typedef u16 u16x4 __attribute__((ext_vector_type(4)));
typedef u16 u16x8 __attribute__((ext_vector_type(8)));
typedef unsigned u32x4 __attribute__((ext_vector_type(4)));

__device__ __forceinline__ float b2f(u16 v) {
  union { unsigned u; float f; } x; x.u = ((unsigned)v) << 16; return x.f;
}
__device__ __forceinline__ u16 f2b(float f) {
  unsigned u = __float_as_uint(f);
  unsigned r = (u + 0x7FFFu + ((u >> 16) & 1u)) >> 16;
  return (u16)r;
}
// dtype-agnostic input read: bf==1 -> bf16, bf==0 -> f32
__device__ __forceinline__ float rin(const void* p, size_t i, int bf) {
  return bf ? b2f(((const u16*)p)[i]) : ((const float*)p)[i];
}
__device__ __forceinline__ void async16(const void* g, void* l) {
  __builtin_amdgcn_global_load_lds((const __attribute__((address_space(1))) unsigned*)g,
                                   (__attribute__((address_space(3))) unsigned*)l, 16, 0, 0);
}

// ---- detect input dtype from w0's bit patterns (low u16 of each u32 word) ----
__global__ void detect_kernel(const unsigned* __restrict__ w0, int* __restrict__ flag) {
  if (threadIdx.x == 0) {
    int ok = 1;
    for (int i = 0; i < 64; ++i) {
      unsigned lo = w0[i] & 0xFFFFu;
      unsigned e = (lo >> 7) & 0xFFu;   // bf16 biased exponent if data is bf16
      if (e < 100u || e > 126u) { ok = 0; break; }
    }
    flag[0] = ok;   // 1 = bf16 inputs/outputs, 0 = f32 inputs/outputs
  }
}

// ---- all three style GEMMs in one launch: s[b,i] = sum_z w[b,z]*sW[i,z] + sB[i]
// grid (8 ochunks, 8 batches, 3 mats), 256 thr: 64 outputs x 4 lanes of 128 MACs
__global__ void styleall_kernel(const void* __restrict__ w,
                                const void* __restrict__ sW0, const void* __restrict__ sB0,
                                const void* __restrict__ sW1, const void* __restrict__ sB1,
                                const void* __restrict__ sWR, const void* __restrict__ sBR,
                                float* __restrict__ s0, float* __restrict__ s1,
                                float* __restrict__ sR, const int* __restrict__ flag) {
  const int bf = flag[0];
  const int mat = blockIdx.z, b = blockIdx.y, oc = blockIdx.x;
  const void* sW = (mat == 0) ? sW0 : ((mat == 1) ? sW1 : sWR);
  const void* sB = (mat == 0) ? sB0 : ((mat == 1) ? sB1 : sBR);
  float* out = (mat == 0) ? s0 : ((mat == 1) ? s1 : sR);
  const int tid = threadIdx.x;
  const int i = oc * 64 + (tid >> 2), q = tid & 3;
  float acc = 0.f;
  if (bf) {
    const u16* rp = (const u16*)sW + (size_t)i * 512 + q * 128;
    const u16* wp = (const u16*)w + b * 512 + q * 128;
    for (int z = 0; z < 128; z += 8) {
      u16x8 a = *(const u16x8*)(rp + z), c = *(const u16x8*)(wp + z);
#pragma unroll
      for (int j = 0; j < 8; ++j) acc += b2f(a[j]) * b2f(c[j]);
    }
  } else {
    const float* rp = (const float*)sW + (size_t)i * 512 + q * 128;
    const float* wp = (const float*)w + b * 512 + q * 128;
    for (int z = 0; z < 128; z += 4) {
      f32x4 a = *(const f32x4*)(rp + z), c = *(const f32x4*)(wp + z);
#pragma unroll
      for (int j = 0; j < 4; ++j) acc += a[j] * c[j];
    }
  }
  acc += __shfl_xor(acc, 1, 64);
  acc += __shfl_xor(acc, 2, 64);
  if (q == 0) out[b * 512 + i] = acc + rin(sB, i, bf);
}

// ---- demod d[b,o] = rsqrt(sum_i (sum_t W[o,i,t]^2) * s[b,i]^2 + eps); repack W -> Wp[t][o][i]
__global__ void demod_kernel(const void* __restrict__ W, const float* __restrict__ s,
                             float* __restrict__ d, u16* __restrict__ Wp,
                             const int* __restrict__ flag) {
  const int bf = flag[0];
  const int o = blockIdx.x, tid = threadIdx.x, lane = tid & 63, wv = tid >> 6;
  __shared__ float wsq[512];
  for (int i = tid; i < 512; i += 256) {
    float ss = 0.f;
#pragma unroll
    for (int t = 0; t < 9; ++t) {
      const float f = rin(W, (size_t)(o * 512 + i) * 9 + t, bf);
      ss += f * f;
      Wp[t * 262144 + o * 512 + i] = f2b(f);
    }
    wsq[i] = ss;
  }
  __syncthreads();
#pragma unroll
  for (int bb = 0; bb < 2; ++bb) {
    const int b = wv * 2 + bb;
    float part = 0.f;
    for (int i = lane; i < 512; i += 64) { const float sv = s[b * 512 + i]; part += wsq[i] * sv * sv; }
#pragma unroll
    for (int st = 1; st < 64; st <<= 1) part += __shfl_xor(part, st, 64);
    if (lane == 0) d[b * 512 + o] = rsqrtf(part + 1e-8f);
  }
}

// ---- bilinear 2x upsample * s0 -> bf16 NHWC scratch [bl][4096][512] inside d_out x-region
__global__ void upsample_kernel(const void* __restrict__ maps, const float* __restrict__ s,
                                void* __restrict__ outb, int b_base,
                                const int* __restrict__ flag) {
  const int bf = flag[0];
  const size_t esz = bf ? 2 : 4;
  u16* xg = (u16*)((char*)outb + (98304 + (size_t)(b_base >> 2) * 8388608) * esz);
  const int oy = blockIdx.x;       // 0..63
  const int i0 = blockIdx.y * 32;  // channel chunk
  const int bl = blockIdx.z;       // local batch 0..3
  const int bg = b_base + bl;
  const int tid = threadIdx.x;
  __shared__ float it[32][2][33];
  const int m = oy >> 1;
  int iy0, iy1; float wy0, wy1;
  if ((oy & 1) == 0) { iy0 = (m > 0) ? m - 1 : 0; iy1 = m; wy0 = 0.25f; wy1 = 0.75f; }
  else               { iy0 = m; iy1 = (m < 31) ? m + 1 : 31; wy0 = 0.75f; wy1 = 0.25f; }
#pragma unroll
  for (int k = 0; k < 8; ++k) {
    const int e = tid + k * 256;  // 32c x 2rows x 32x = 2048
    const int c = e >> 6, wsel = (e >> 5) & 1, x = e & 31;
    const int iy = wsel ? iy1 : iy0;
    it[c][wsel][x] = rin(maps, ((size_t)(bg * 512 + i0 + c) * 32 + iy) * 32 + x, bf);
  }
  __syncthreads();
#pragma unroll
  for (int k = 0; k < 8; ++k) {
    const int e = tid + k * 256;  // 64 xx * 32 c = 2048
    const int xx = e >> 5, c = e & 31;
    const int mx = xx >> 1;
    int ix0, ix1; float wx0, wx1;
    if ((xx & 1) == 0) { ix0 = (mx > 0) ? mx - 1 : 0; ix1 = mx; wx0 = 0.25f; wx1 = 0.75f; }
    else               { ix0 = mx; ix1 = (mx < 31) ? mx + 1 : 31; wx0 = 0.75f; wx1 = 0.25f; }
    const float r0 = wx0 * it[c][0][ix0] + wx1 * it[c][0][ix1];
    const float r1 = wx0 * it[c][1][ix0] + wx1 * it[c][1][ix1];
    const float v = (wy0 * r0 + wy1 * r1) * s[bg * 512 + i0 + c];
    xg[((size_t)(bl * 4096) + oy * 64 + xx) * 512 + i0 + c] = f2b(v);
  }
}

__global__ void zero_kernel(u32x4* __restrict__ p, int n16) {
  const int i = blockIdx.x * 256 + threadIdx.x;
  if (i < n16) { u32x4 z = {0, 0, 0, 0}; p[i] = z; }
}

// ---- conv0: implicit GEMM 3x3 over no-halo NHWC scratch; boundary staging lanes
// redirect to a zeroed dummy buffer so global_load_lds needs no exec masking.
// epilogue: lrelu(acc*dm + b + ns*noise)*s1 -> actB halo NHWC [bl][66][66][512]
__global__ __launch_bounds__(256) void conv0_kernel(
    const void* __restrict__ outb, const u16* __restrict__ Wp,
    const float* __restrict__ dmod, const void* __restrict__ bias,
    const void* __restrict__ nsc, const void* __restrict__ noise,
    const float* __restrict__ snext, u16* __restrict__ actB,
    const u16* __restrict__ zbuf, int b_base, const int* __restrict__ flag) {
  const int bf = flag[0];
  const size_t esz = bf ? 2 : 4;
  const u16* xg = (const u16*)((const char*)outb + (98304 + (size_t)(b_base >> 2) * 8388608) * esz);
  __shared__ __attribute__((aligned(16))) u16 Alds[4096];
  __shared__ __attribute__((aligned(16))) u16 Blds[4096];
  const int tid = threadIdx.x, lane = tid & 63, w = tid >> 6;
  const int wm = w >> 1, wn = w & 1;
  const int n0 = blockIdx.x * 128, o0 = blockIdx.y * 128;
  const int bl = blockIdx.z, bg = b_base + bl;

  const int srow = w * 32 + (lane >> 2);
  const int scol = (lane & 3) * 8;
  const size_t aA = (size_t)(o0 + srow) * 512 + scol;
  const int p0 = n0 + srow, p1 = p0 + 16;
  const int oy0 = p0 >> 6, ox0 = p0 & 63;
  const int oy1 = p1 >> 6, ox1 = p1 & 63;
  u16* lA0 = &Alds[w * 1024]; u16* lA1 = &Alds[w * 1024 + 512];
  u16* lB0 = &Blds[w * 1024]; u16* lB1 = &Blds[w * 1024 + 512];

  f32x4 acc[4][4] = {};
  const int q = lane >> 4, mrow = lane & 15;

#pragma unroll 1
  for (int t = 0; t < 9; ++t) {
    const int ty = t / 3, tx = t % 3;
    const size_t wbase = (size_t)t * 262144;
    const int iy0 = oy0 + ty - 1, ix0 = ox0 + tx - 1;
    const int iy1 = oy1 + ty - 1, ix1 = ox1 + tx - 1;
    const bool ok0 = ((unsigned)iy0 < 64u) && ((unsigned)ix0 < 64u);
    const bool ok1 = ((unsigned)iy1 < 64u) && ((unsigned)ix1 < 64u);
    const u16* baseB0 = ok0 ? (xg + (((size_t)(bl * 4096) + iy0 * 64 + ix0) * 512 + scol)) : (zbuf + scol);
    const u16* baseB1 = ok1 ? (xg + (((size_t)(bl * 4096) + iy1 * 64 + ix1) * 512 + scol)) : (zbuf + scol);
    const u16* baseA = Wp + wbase + aA;
#pragma unroll 1
    for (int kc = 0; kc < 16; ++kc) {
      const int ko = kc * 32;
      __syncthreads();                 // prior iteration's LDS reads complete
      async16(baseA + ko, lA0);
      async16(baseA + ko + 16 * 512, lA1);
      async16(baseB0 + ko, lB0);
      async16(baseB1 + ko, lB1);
      __syncthreads();                 // vmcnt(0)-drained barrier: staging visible
      bf16x8 af[4], bfv[4];
#pragma unroll
      for (int mi = 0; mi < 4; ++mi)
        af[mi] = *(const bf16x8*)&Alds[(wm * 64 + mi * 16 + mrow) * 32 + q * 8];
#pragma unroll
      for (int ni = 0; ni < 4; ++ni)
        bfv[ni] = *(const bf16x8*)&Blds[(wn * 64 + ni * 16 + mrow) * 32 + q * 8];
#pragma unroll
      for (int mi = 0; mi < 4; ++mi)
#pragma unroll
        for (int ni = 0; ni < 4; ++ni)
          acc[mi][ni] = __builtin_amdgcn_mfma_f32_16x16x32_bf16(af[mi], bfv[ni], acc[mi][ni], 0, 0, 0);
    }
  }

#pragma unroll
  for (int mi = 0; mi < 4; ++mi) {
    const int o = o0 + wm * 64 + mi * 16 + q * 4;
    const f32x4 dv = *(const f32x4*)&dmod[bg * 512 + o];
    const f32x4 sv = *(const f32x4*)&snext[bg * 512 + o];
    float bv[4], nv[4];
#pragma unroll
    for (int r = 0; r < 4; ++r) { bv[r] = rin(bias, o + r, bf); nv[r] = rin(nsc, o + r, bf); }
#pragma unroll
    for (int ni = 0; ni < 4; ++ni) {
      const int p = n0 + wn * 64 + ni * 16 + mrow;
      const float np = rin(noise, (size_t)bg * 4096 + p, bf);
      u16x4 pack;
#pragma unroll
      for (int r = 0; r < 4; ++r) {
        float v = acc[mi][ni][r] * dv[r] + bv[r] + nv[r] * np;
        v = (v >= 0.f) ? v : 0.2f * v;
        pack[r] = f2b(v * sv[r]);
      }
      const int oy = p >> 6, ox = p & 63;
      *(u16x4*)&actB[((size_t)(bl * 4356) + (oy + 1) * 66 + (ox + 1)) * 512 + o] = pack;
    }
  }
}

// ---- conv1: implicit GEMM 3x3 over halo NHWC actB.
// epilogue: x = lrelu(acc*dm + b + ns*noise) -> d_out x-region (dual dtype, NCHW);
//           rgb partials: atomicAdd rgbacc[b][c][p] += sum_o rgbW[c][o]*(x*sR)[o]
__global__ __launch_bounds__(256) void conv1_kernel(
    const u16* __restrict__ actB, const u16* __restrict__ Wp,
    const float* __restrict__ dmod, const void* __restrict__ bias,
    const void* __restrict__ nsc, const void* __restrict__ noise,
    const float* __restrict__ sR, const void* __restrict__ rgbW,
    float* __restrict__ rgbacc, void* __restrict__ outb, int b_base,
    const int* __restrict__ flag) {
  const int bf = flag[0];
  __shared__ __attribute__((aligned(16))) u16 Alds[4096];
  __shared__ __attribute__((aligned(16))) u16 Blds[4096];
  __shared__ float rgbWl[1536];
  const int tid = threadIdx.x, lane = tid & 63, w = tid >> 6;
  const int wm = w >> 1, wn = w & 1;
  const int n0 = blockIdx.x * 128, o0 = blockIdx.y * 128;
  const int bl = blockIdx.z, bg = b_base + bl;

  for (int e = tid; e < 1536; e += 256) rgbWl[e] = rin(rgbW, e, bf);

  const int srow = w * 32 + (lane >> 2);
  const int scol = (lane & 3) * 8;
  const size_t aA = (size_t)(o0 + srow) * 512 + scol;
  const int p0 = n0 + srow, p1 = p0 + 16;
  const size_t aB0 = ((size_t)(bl * 4356) + (p0 >> 6) * 66 + (p0 & 63)) * 512 + scol;
  const size_t aB1 = ((size_t)(bl * 4356) + (p1 >> 6) * 66 + (p1 & 63)) * 512 + scol;
  u16* lA0 = &Alds[w * 1024]; u16* lA1 = &Alds[w * 1024 + 512];
  u16* lB0 = &Blds[w * 1024]; u16* lB1 = &Blds[w * 1024 + 512];

  f32x4 acc[4][4] = {};
  const int q = lane >> 4, mrow = lane & 15;

#pragma unroll 1
  for (int t = 0; t < 9; ++t) {
    const int toffB = ((t / 3) * 66 + (t % 3)) * 512;
    const u16* baseA = Wp + (size_t)t * 262144 + aA;
    const u16* baseB0 = actB + aB0 + toffB;
    const u16* baseB1 = actB + aB1 + toffB;
#pragma unroll 1
    for (int kc = 0; kc < 16; ++kc) {
      const int ko = kc * 32;
      __syncthreads();
      async16(baseA + ko, lA0);
      async16(baseA + ko + 16 * 512, lA1);
      async16(baseB0 + ko, lB0);
      async16(baseB1 + ko, lB1);
      __syncthreads();
      bf16x8 af[4], bfv[4];
#pragma unroll
      for (int mi = 0; mi < 4; ++mi)
        af[mi] = *(const bf16x8*)&Alds[(wm * 64 + mi * 16 + mrow) * 32 + q * 8];
#pragma unroll
      for (int ni = 0; ni < 4; ++ni)
        bfv[ni] = *(const bf16x8*)&Blds[(wn * 64 + ni * 16 + mrow) * 32 + q * 8];
#pragma unroll
      for (int mi = 0; mi < 4; ++mi)
#pragma unroll
        for (int ni = 0; ni < 4; ++ni)
          acc[mi][ni] = __builtin_amdgcn_mfma_f32_16x16x32_bf16(af[mi], bfv[ni], acc[mi][ni], 0, 0, 0);
    }
  }

  const size_t esz = bf ? 2 : 4;
  char* xreg = (char*)outb + 98304 * esz;
  float racc[4][3] = {};
#pragma unroll
  for (int mi = 0; mi < 4; ++mi) {
    const int o = o0 + wm * 64 + mi * 16 + q * 4;
    const f32x4 dv = *(const f32x4*)&dmod[bg * 512 + o];
    const f32x4 srv = *(const f32x4*)&sR[bg * 512 + o];
    float bv[4], nv[4], w0l[4], w1l[4], w2l[4];
#pragma unroll
    for (int r = 0; r < 4; ++r) {
      bv[r] = rin(bias, o + r, bf); nv[r] = rin(nsc, o + r, bf);
      w0l[r] = rgbWl[o + r]; w1l[r] = rgbWl[512 + o + r]; w2l[r] = rgbWl[1024 + o + r];
    }
#pragma unroll
    for (int ni = 0; ni < 4; ++ni) {
      const int p = n0 + wn * 64 + ni * 16 + mrow;
      const float np = rin(noise, (size_t)bg * 4096 + p, bf);
#pragma unroll
      for (int r = 0; r < 4; ++r) {
        float v = acc[mi][ni][r] * dv[r] + bv[r] + nv[r] * np;
        v = (v >= 0.f) ? v : 0.2f * v;
        const size_t xi = (size_t)(bg * 512 + o + r) * 4096 + p;
        if (bf) ((u16*)xreg)[xi] = f2b(v); else ((float*)xreg)[xi] = v;
        const float xr = v * srv[r];
        racc[ni][0] += w0l[r] * xr;
        racc[ni][1] += w1l[r] * xr;
        racc[ni][2] += w2l[r] * xr;
      }
    }
  }
#pragma unroll
  for (int ni = 0; ni < 4; ++ni) {
    const int p = n0 + wn * 64 + ni * 16 + mrow;
#pragma unroll
    for (int c = 0; c < 3; ++c) {
      float t = racc[ni][c];
      t += __shfl_xor(t, 16, 64);
      t += __shfl_xor(t, 32, 64);
      if (lane < 16) atomicAdd(&rgbacc[(size_t)(bg * 3 + c) * 4096 + p], t);
    }
  }
}

// ---- finalize rgb: out[b,c,p] = up2(rgb) + rgbB[c] + rgbacc[b,c,p]
__global__ void rgbfin_kernel(const float* __restrict__ rgbacc, const void* __restrict__ rgbB,
                              const void* __restrict__ rgb, void* __restrict__ outb,
                              const int* __restrict__ flag) {
  const int bf = flag[0];
  const int g = blockIdx.x * 256 + threadIdx.x;  // 0..32767
  const int b = g >> 12, p = g & 4095;
  const int oy = p >> 6, ox = p & 63;
  const int m = oy >> 1; int iy0, iy1; float wy0, wy1;
  if ((oy & 1) == 0) { iy0 = (m > 0) ? m - 1 : 0; iy1 = m; wy0 = 0.25f; wy1 = 0.75f; }
  else               { iy0 = m; iy1 = (m < 31) ? m + 1 : 31; wy0 = 0.75f; wy1 = 0.25f; }
  const int mx = ox >> 1; int ix0, ix1; float wx0, wx1;
  if ((ox & 1) == 0) { ix0 = (mx > 0) ? mx - 1 : 0; ix1 = mx; wx0 = 0.25f; wx1 = 0.75f; }
  else               { ix0 = mx; ix1 = (mx < 31) ? mx + 1 : 31; wx0 = 0.75f; wx1 = 0.25f; }
#pragma unroll
  for (int c = 0; c < 3; ++c) {
    const size_t rb = (size_t)(b * 3 + c) * 1024;
    const float up = wy0 * (wx0 * rin(rgb, rb + iy0 * 32 + ix0, bf) + wx1 * rin(rgb, rb + iy0 * 32 + ix1, bf))
                   + wy1 * (wx0 * rin(rgb, rb + iy1 * 32 + ix0, bf) + wx1 * rin(rgb, rb + iy1 * 32 + ix1, bf));
    const float v = up + rin(rgbB, c, bf) + rgbacc[(size_t)(b * 3 + c) * 4096 + p];
    const size_t oi = ((size_t)(b * 3 + c) << 12) + p;
    if (bf) ((u16*)outb)[oi] = f2b(v); else ((float*)outb)[oi] = v;
  }
}

// ---------------- workspace layout (bytes), total ~26.5 MB ----------------
// flag:0(64)  s0:1024  s1:17408  sR:33792  dm0:50176  dm1:66560
// zbuf:82944 (4096, zeroed)  rgbacc:87040 (393216)  -> 480256
// Wp0:480256 (4718592)  Wp1:5198848 (4718592)
// actB:9917440 (17842176) -> end 27759616

extern "C" void kernel_launch(void* const* d_in, const int* in_sizes, int n_in,
                              void* d_out, int out_size, void* d_ws, size_t ws_size,
                              hipStream_t stream) {
  const void* maps   = d_in[0];
  const void* wlat   = d_in[1];
  const void* rgb    = d_in[2];
  const void* noise0 = d_in[3];
  const void* noise1 = d_in[4];
  const void* w0     = d_in[5];
  const void* b0     = d_in[6];
  const void* sW0    = d_in[7];
  const void* sB0    = d_in[8];
  const void* ns0    = d_in[9];
  const void* w1     = d_in[10];
  const void* b1     = d_in[11];
  const void* sW1    = d_in[12];
  const void* sB1    = d_in[13];
  const void* ns1    = d_in[14];
  const void* rgbW   = d_in[15];
  const void* rgbB   = d_in[16];
  const void* rgbSW  = d_in[17];
  const void* rgbSB  = d_in[18];

  char* ws = (char*)d_ws;
  int*   flg    = (int*)(ws + 0);
  float* s0     = (float*)(ws + 1024);
  float* s1     = (float*)(ws + 17408);
  float* sR     = (float*)(ws + 33792);
  float* dm0    = (float*)(ws + 50176);
  float* dm1    = (float*)(ws + 66560);
  u16*   zbuf   = (u16*)(ws + 82944);
  float* rgbacc = (float*)(ws + 87040);
  u16*   Wp0    = (u16*)(ws + 480256);
  u16*   Wp1    = (u16*)(ws + 5198848);
  u16*   actB   = (u16*)(ws + 9917440);

  detect_kernel<<<1, 64, 0, stream>>>((const unsigned*)w0, flg);
  styleall_kernel<<<dim3(8, 8, 3), 256, 0, stream>>>(wlat, sW0, sB0, sW1, sB1, rgbSW, rgbSB,
                                                     s0, s1, sR, flg);
  demod_kernel<<<512, 256, 0, stream>>>(w0, s0, dm0, Wp0, flg);
  demod_kernel<<<512, 256, 0, stream>>>(w1, s1, dm1, Wp1, flg);
  // zero zbuf + rgbacc (contiguous), and actB halo once (interior overwritten per half)
  zero_kernel<<<98, 256, 0, stream>>>((u32x4*)zbuf, 24832);
  zero_kernel<<<4357, 256, 0, stream>>>((u32x4*)actB, 1115136);

  for (int half = 0; half < 2; ++half) {
    const int b_base = half * 4;
    upsample_kernel<<<dim3(64, 16, 4), 256, 0, stream>>>(maps, s0, d_out, b_base, flg);
    conv0_kernel<<<dim3(32, 4, 4), 256, 0, stream>>>(d_out, Wp0, dm0, b0, ns0, noise0, s1,
                                                     actB, zbuf, b_base, flg);
    conv1_kernel<<<dim3(32, 4, 4), 256, 0, stream>>>(actB, Wp1, dm1, b1, ns1, noise1, sR,
                                                     rgbW, rgbacc, d_out, b_base, flg);
  }
  rgbfin_kernel<<<128, 256, 0, stream>>>(rgbacc, rgbB, rgb, d_out, flg);
}

// Round 6
// 516.656 us; speedup vs baseline: 1.8764x; 1.1476x over previous
//
#include <hip/hip_runtime.h>

typedef unsigned short u16;
typedef short bf16x8 __attribute__((ext_vector_type(8)));
typedef float f32x4 __attribute__((ext_vector_type(4)));
typedef u16 u16x4 __attribute__((ext_vector_type(4)));
typedef u16 u16x8 __attribute__((ext_vector_type(8)));
typedef unsigned u32x4 __attribute__((ext_vector_type(4)));

__device__ __forceinline__ float b2f(u16 v) {
  union { unsigned u; float f; } x; x.u = ((unsigned)v) << 16; return x.f;
}
__device__ __forceinline__ u16 f2b(float f) {
  unsigned u = __float_as_uint(f);
  unsigned r = (u + 0x7FFFu + ((u >> 16) & 1u)) >> 16;
  return (u16)r;
}
// dtype-agnostic input read: bf==1 -> bf16, bf==0 -> f32
__device__ __forceinline__ float rin(const void* p, size_t i, int bf) {
  return bf ? b2f(((const u16*)p)[i]) : ((const float*)p)[i];
}
__device__ __forceinline__ void async16(const void* g, void* l) {
  __builtin_amdgcn_global_load_lds((const __attribute__((address_space(1))) unsigned*)g,
                                   (__attribute__((address_space(3))) unsigned*)l, 16, 0, 0);
}

// ---- detect input dtype from w0's bit patterns (low u16 of each u32 word) ----
// one parallel load per lane + ballot (was: 64 serial dependent loads ~20us)
__global__ void detect_kernel(const unsigned* __restrict__ w0, int* __restrict__ flag) {
  const int i = threadIdx.x;  // 64 lanes
  const unsigned lo = w0[i] & 0xFFFFu;
  const unsigned e = (lo >> 7) & 0xFFu;  // bf16 biased exponent if data is bf16
  const unsigned long long bad = __ballot(e < 100u || e > 126u);
  if (i == 0) flag[0] = (bad == 0ull) ? 1 : 0;  // 1 = bf16, 0 = f32
}

// ---- all three style GEMMs in one launch: s[b,i] = sum_z w[b,z]*sW[i,z] + sB[i]
__global__ void styleall_kernel(const void* __restrict__ w,
                                const void* __restrict__ sW0, const void* __restrict__ sB0,
                                const void* __restrict__ sW1, const void* __restrict__ sB1,
                                const void* __restrict__ sWR, const void* __restrict__ sBR,
                                float* __restrict__ s0, float* __restrict__ s1,
                                float* __restrict__ sR, const int* __restrict__ flag) {
  const int bf = flag[0];
  const int mat = blockIdx.z, b = blockIdx.y, oc = blockIdx.x;
  const void* sW = (mat == 0) ? sW0 : ((mat == 1) ? sW1 : sWR);
  const void* sB = (mat == 0) ? sB0 : ((mat == 1) ? sB1 : sBR);
  float* out = (mat == 0) ? s0 : ((mat == 1) ? s1 : sR);
  const int tid = threadIdx.x;
  const int i = oc * 64 + (tid >> 2), q = tid & 3;
  float acc = 0.f;
  if (bf) {
    const u16* rp = (const u16*)sW + (size_t)i * 512 + q * 128;
    const u16* wp = (const u16*)w + b * 512 + q * 128;
    for (int z = 0; z < 128; z += 8) {
      u16x8 a = *(const u16x8*)(rp + z), c = *(const u16x8*)(wp + z);
#pragma unroll
      for (int j = 0; j < 8; ++j) acc += b2f(a[j]) * b2f(c[j]);
    }
  } else {
    const float* rp = (const float*)sW + (size_t)i * 512 + q * 128;
    const float* wp = (const float*)w + b * 512 + q * 128;
    for (int z = 0; z < 128; z += 4) {
      f32x4 a = *(const f32x4*)(rp + z), c = *(const f32x4*)(wp + z);
#pragma unroll
      for (int j = 0; j < 4; ++j) acc += a[j] * c[j];
    }
  }
  acc += __shfl_xor(acc, 1, 64);
  acc += __shfl_xor(acc, 2, 64);
  if (q == 0) out[b * 512 + i] = acc + rin(sB, i, bf);
}

// ---- demod d[b,o] = rsqrt(sum_i (sum_t W[o,i,t]^2) * s[b,i]^2 + eps); repack W -> Wp[t][o][i]
__global__ void demod_kernel(const void* __restrict__ W, const float* __restrict__ s,
                             float* __restrict__ d, u16* __restrict__ Wp,
                             const int* __restrict__ flag) {
  const int bf = flag[0];
  const int o = blockIdx.x, tid = threadIdx.x, lane = tid & 63, wv = tid >> 6;
  __shared__ float wsq[512];
  for (int i = tid; i < 512; i += 256) {
    float ss = 0.f;
#pragma unroll
    for (int t = 0; t < 9; ++t) {
      const float f = rin(W, (size_t)(o * 512 + i) * 9 + t, bf);
      ss += f * f;
      Wp[t * 262144 + o * 512 + i] = f2b(f);
    }
    wsq[i] = ss;
  }
  __syncthreads();
#pragma unroll
  for (int bb = 0; bb < 2; ++bb) {
    const int b = wv * 2 + bb;
    float part = 0.f;
    for (int i = lane; i < 512; i += 64) { const float sv = s[b * 512 + i]; part += wsq[i] * sv * sv; }
#pragma unroll
    for (int st = 1; st < 64; st <<= 1) part += __shfl_xor(part, st, 64);
    if (lane == 0) d[b * 512 + o] = rsqrtf(part + 1e-8f);
  }
}

// ---- bilinear 2x upsample * s0 -> bf16 NHWC scratch [bl][4096][512] inside d_out x-region
__global__ void upsample_kernel(const void* __restrict__ maps, const float* __restrict__ s,
                                void* __restrict__ outb, int b_base,
                                const int* __restrict__ flag) {
  const int bf = flag[0];
  const size_t esz = bf ? 2 : 4;
  u16* xg = (u16*)((char*)outb + (98304 + (size_t)(b_base >> 2) * 8388608) * esz);
  const int oy = blockIdx.x;       // 0..63
  const int i0 = blockIdx.y * 32;  // channel chunk
  const int bl = blockIdx.z;       // local batch
  const int bg = b_base + bl;
  const int tid = threadIdx.x;
  __shared__ float it[32][2][33];
  const int m = oy >> 1;
  int iy0, iy1; float wy0, wy1;
  if ((oy & 1) == 0) { iy0 = (m > 0) ? m - 1 : 0; iy1 = m; wy0 = 0.25f; wy1 = 0.75f; }
  else               { iy0 = m; iy1 = (m < 31) ? m + 1 : 31; wy0 = 0.75f; wy1 = 0.25f; }
#pragma unroll
  for (int k = 0; k < 8; ++k) {
    const int e = tid + k * 256;  // 32c x 2rows x 32x = 2048
    const int c = e >> 6, wsel = (e >> 5) & 1, x = e & 31;
    const int iy = wsel ? iy1 : iy0;
    it[c][wsel][x] = rin(maps, ((size_t)(bg * 512 + i0 + c) * 32 + iy) * 32 + x, bf);
  }
  __syncthreads();
#pragma unroll
  for (int k = 0; k < 8; ++k) {
    const int e = tid + k * 256;  // 64 xx * 32 c = 2048
    const int xx = e >> 5, c = e & 31;
    const int mx = xx >> 1;
    int ix0, ix1; float wx0, wx1;
    if ((xx & 1) == 0) { ix0 = (mx > 0) ? mx - 1 : 0; ix1 = mx; wx0 = 0.25f; wx1 = 0.75f; }
    else               { ix0 = mx; ix1 = (mx < 31) ? mx + 1 : 31; wx0 = 0.75f; wx1 = 0.25f; }
    const float r0 = wx0 * it[c][0][ix0] + wx1 * it[c][0][ix1];
    const float r1 = wx0 * it[c][1][ix0] + wx1 * it[c][1][ix1];
    const float v = (wy0 * r0 + wy1 * r1) * s[bg * 512 + i0 + c];
    xg[((size_t)(bl * 4096) + oy * 64 + xx) * 512 + i0 + c] = f2b(v);
  }
}

__global__ void zero_kernel(u32x4* __restrict__ p, int n16) {
  const int i = blockIdx.x * 256 + threadIdx.x;
  if (i < n16) { u32x4 z = {0, 0, 0, 0}; p[i] = z; }
}

// ---- conv0: implicit GEMM 3x3, BK=64 (two 32-wide sub-chunks in separate LDS halves
// so the 64B row stride / fragment geometry is unchanged; 72 barrier-pairs vs 144).
// Boundary staging lanes redirect to a zeroed dummy buffer (no exec masking on async).
// epilogue: lrelu(acc*dm + b + ns*noise)*s1 -> actB halo NHWC [bl][66][66][512]
__global__ __launch_bounds__(256) void conv0_kernel(
    const void* __restrict__ outb, const u16* __restrict__ Wp,
    const float* __restrict__ dmod, const void* __restrict__ bias,
    const void* __restrict__ nsc, const void* __restrict__ noise,
    const float* __restrict__ snext, u16* __restrict__ actB,
    const u16* __restrict__ zbuf, int b_base, const int* __restrict__ flag) {
  const int bf = flag[0];
  const size_t esz = bf ? 2 : 4;
  const u16* xg = (const u16*)((const char*)outb + (98304 + (size_t)(b_base >> 2) * 8388608) * esz);
  __shared__ __attribute__((aligned(16))) u16 Alds[8192];
  __shared__ __attribute__((aligned(16))) u16 Blds[8192];
  const int tid = threadIdx.x, lane = tid & 63, w = tid >> 6;
  const int wm = w >> 1, wn = w & 1;
  const int n0 = blockIdx.x * 128, o0 = blockIdx.y * 128;
  const int bl = blockIdx.z, bg = b_base + bl;

  const int srow = w * 32 + (lane >> 2);
  const int scol = (lane & 3) * 8;
  const size_t aA = (size_t)(o0 + srow) * 512 + scol;
  const int p0 = n0 + srow, p1 = p0 + 16;
  const int oy0 = p0 >> 6, ox0 = p0 & 63;
  const int oy1 = p1 >> 6, ox1 = p1 & 63;
  u16* lA0 = &Alds[w * 1024]; u16* lA1 = &Alds[w * 1024 + 512];
  u16* lB0 = &Blds[w * 1024]; u16* lB1 = &Blds[w * 1024 + 512];

  f32x4 acc[4][4] = {};
  const int q = lane >> 4, mrow = lane & 15;

#pragma unroll 1
  for (int t = 0; t < 9; ++t) {
    const int ty = t / 3, tx = t % 3;
    const size_t wbase = (size_t)t * 262144;
    const int iy0 = oy0 + ty - 1, ix0 = ox0 + tx - 1;
    const int iy1 = oy1 + ty - 1, ix1 = ox1 + tx - 1;
    const bool ok0 = ((unsigned)iy0 < 64u) && ((unsigned)ix0 < 64u);
    const bool ok1 = ((unsigned)iy1 < 64u) && ((unsigned)ix1 < 64u);
    const u16* baseB0 = ok0 ? (xg + (((size_t)(bl * 4096) + iy0 * 64 + ix0) * 512 + scol)) : (zbuf + scol);
    const u16* baseB1 = ok1 ? (xg + (((size_t)(bl * 4096) + iy1 * 64 + ix1) * 512 + scol)) : (zbuf + scol);
    const u16* baseA = Wp + wbase + aA;
#pragma unroll 1
    for (int kc = 0; kc < 8; ++kc) {
      const int ko = kc * 64;
      __syncthreads();                 // prior iteration's LDS reads complete
      async16(baseA + ko, lA0);
      async16(baseA + ko + 16 * 512, lA1);
      async16(baseA + ko + 32, lA0 + 4096);
      async16(baseA + ko + 32 + 16 * 512, lA1 + 4096);
      async16(baseB0 + ko, lB0);
      async16(baseB1 + ko, lB1);
      async16(baseB0 + ko + 32, lB0 + 4096);
      async16(baseB1 + ko + 32, lB1 + 4096);
      __syncthreads();                 // vmcnt-drained barrier: staging visible
#pragma unroll
      for (int kk = 0; kk < 2; ++kk) {
        bf16x8 af[4], bfv[4];
#pragma unroll
        for (int mi = 0; mi < 4; ++mi)
          af[mi] = *(const bf16x8*)&Alds[kk * 4096 + (wm * 64 + mi * 16 + mrow) * 32 + q * 8];
#pragma unroll
        for (int ni = 0; ni < 4; ++ni)
          bfv[ni] = *(const bf16x8*)&Blds[kk * 4096 + (wn * 64 + ni * 16 + mrow) * 32 + q * 8];
#pragma unroll
        for (int mi = 0; mi < 4; ++mi)
#pragma unroll
          for (int ni = 0; ni < 4; ++ni)
            acc[mi][ni] = __builtin_amdgcn_mfma_f32_16x16x32_bf16(af[mi], bfv[ni], acc[mi][ni], 0, 0, 0);
      }
    }
  }

#pragma unroll
  for (int mi = 0; mi < 4; ++mi) {
    const int o = o0 + wm * 64 + mi * 16 + q * 4;
    const f32x4 dv = *(const f32x4*)&dmod[bg * 512 + o];
    const f32x4 sv = *(const f32x4*)&snext[bg * 512 + o];
    float bv[4], nv[4];
#pragma unroll
    for (int r = 0; r < 4; ++r) { bv[r] = rin(bias, o + r, bf); nv[r] = rin(nsc, o + r, bf); }
#pragma unroll
    for (int ni = 0; ni < 4; ++ni) {
      const int p = n0 + wn * 64 + ni * 16 + mrow;
      const float np = rin(noise, (size_t)bg * 4096 + p, bf);
      u16x4 pack;
#pragma unroll
      for (int r = 0; r < 4; ++r) {
        float v = acc[mi][ni][r] * dv[r] + bv[r] + nv[r] * np;
        v = (v >= 0.f) ? v : 0.2f * v;
        pack[r] = f2b(v * sv[r]);
      }
      const int oy = p >> 6, ox = p & 63;
      *(u16x4*)&actB[((size_t)(bl * 4356) + (oy + 1) * 66 + (ox + 1)) * 512 + o] = pack;
    }
  }
}

// ---- conv1: implicit GEMM 3x3 over halo NHWC actB, BK=64.
// epilogue: x = lrelu(acc*dm + b + ns*noise) -> d_out x-region (dual dtype, NCHW);
//           rgb partials: atomicAdd rgbacc[b][c][p] += sum_o rgbW[c][o]*(x*sR)[o]
__global__ __launch_bounds__(256) void conv1_kernel(
    const u16* __restrict__ actB, const u16* __restrict__ Wp,
    const float* __restrict__ dmod, const void* __restrict__ bias,
    const void* __restrict__ nsc, const void* __restrict__ noise,
    const float* __restrict__ sR, const void* __restrict__ rgbW,
    float* __restrict__ rgbacc, void* __restrict__ outb, int b_base,
    const int* __restrict__ flag) {
  const int bf = flag[0];
  __shared__ __attribute__((aligned(16))) u16 Alds[8192];
  __shared__ __attribute__((aligned(16))) u16 Blds[8192];
  __shared__ float rgbWl[1536];
  const int tid = threadIdx.x, lane = tid & 63, w = tid >> 6;
  const int wm = w >> 1, wn = w & 1;
  const int n0 = blockIdx.x * 128, o0 = blockIdx.y * 128;
  const int bl = blockIdx.z, bg = b_base + bl;

  for (int e = tid; e < 1536; e += 256) rgbWl[e] = rin(rgbW, e, bf);

  const int srow = w * 32 + (lane >> 2);
  const int scol = (lane & 3) * 8;
  const size_t aA = (size_t)(o0 + srow) * 512 + scol;
  const int p0 = n0 + srow, p1 = p0 + 16;
  const size_t aB0 = ((size_t)(bl * 4356) + (p0 >> 6) * 66 + (p0 & 63)) * 512 + scol;
  const size_t aB1 = ((size_t)(bl * 4356) + (p1 >> 6) * 66 + (p1 & 63)) * 512 + scol;
  u16* lA0 = &Alds[w * 1024]; u16* lA1 = &Alds[w * 1024 + 512];
  u16* lB0 = &Blds[w * 1024]; u16* lB1 = &Blds[w * 1024 + 512];

  f32x4 acc[4][4] = {};
  const int q = lane >> 4, mrow = lane & 15;

#pragma unroll 1
  for (int t = 0; t < 9; ++t) {
    const int toffB = ((t / 3) * 66 + (t % 3)) * 512;
    const u16* baseA = Wp + (size_t)t * 262144 + aA;
    const u16* baseB0 = actB + aB0 + toffB;
    const u16* baseB1 = actB + aB1 + toffB;
#pragma unroll 1
    for (int kc = 0; kc < 8; ++kc) {
      const int ko = kc * 64;
      __syncthreads();
      async16(baseA + ko, lA0);
      async16(baseA + ko + 16 * 512, lA1);
      async16(baseA + ko + 32, lA0 + 4096);
      async16(baseA + ko + 32 + 16 * 512, lA1 + 4096);
      async16(baseB0 + ko, lB0);
      async16(baseB1 + ko, lB1);
      async16(baseB0 + ko + 32, lB0 + 4096);
      async16(baseB1 + ko + 32, lB1 + 4096);
      __syncthreads();
#pragma unroll
      for (int kk = 0; kk < 2; ++kk) {
        bf16x8 af[4], bfv[4];
#pragma unroll
        for (int mi = 0; mi < 4; ++mi)
          af[mi] = *(const bf16x8*)&Alds[kk * 4096 + (wm * 64 + mi * 16 + mrow) * 32 + q * 8];
#pragma unroll
        for (int ni = 0; ni < 4; ++ni)
          bfv[ni] = *(const bf16x8*)&Blds[kk * 4096 + (wn * 64 + ni * 16 + mrow) * 32 + q * 8];
#pragma unroll
        for (int mi = 0; mi < 4; ++mi)
#pragma unroll
          for (int ni = 0; ni < 4; ++ni)
            acc[mi][ni] = __builtin_amdgcn_mfma_f32_16x16x32_bf16(af[mi], bfv[ni], acc[mi][ni], 0, 0, 0);
      }
    }
  }

  const size_t esz = bf ? 2 : 4;
  char* xreg = (char*)outb + 98304 * esz;
  float racc[4][3] = {};
#pragma unroll
  for (int mi = 0; mi < 4; ++mi) {
    const int o = o0 + wm * 64 + mi * 16 + q * 4;
    const f32x4 dv = *(const f32x4*)&dmod[bg * 512 + o];
    const f32x4 srv = *(const f32x4*)&sR[bg * 512 + o];
    float bv[4], nv[4], w0l[4], w1l[4], w2l[4];
#pragma unroll
    for (int r = 0; r < 4; ++r) {
      bv[r] = rin(bias, o + r, bf); nv[r] = rin(nsc, o + r, bf);
      w0l[r] = rgbWl[o + r]; w1l[r] = rgbWl[512 + o + r]; w2l[r] = rgbWl[1024 + o + r];
    }
#pragma unroll
    for (int ni = 0; ni < 4; ++ni) {
      const int p = n0 + wn * 64 + ni * 16 + mrow;
      const float np = rin(noise, (size_t)bg * 4096 + p, bf);
#pragma unroll
      for (int r = 0; r < 4; ++r) {
        float v = acc[mi][ni][r] * dv[r] + bv[r] + nv[r] * np;
        v = (v >= 0.f) ? v : 0.2f * v;
        const size_t xi = (size_t)(bg * 512 + o + r) * 4096 + p;
        if (bf) ((u16*)xreg)[xi] = f2b(v); else ((float*)xreg)[xi] = v;
        const float xr = v * srv[r];
        racc[ni][0] += w0l[r] * xr;
        racc[ni][1] += w1l[r] * xr;
        racc[ni][2] += w2l[r] * xr;
      }
    }
  }
#pragma unroll
  for (int ni = 0; ni < 4; ++ni) {
    const int p = n0 + wn * 64 + ni * 16 + mrow;
#pragma unroll
    for (int c = 0; c < 3; ++c) {
      float t = racc[ni][c];
      t += __shfl_xor(t, 16, 64);
      t += __shfl_xor(t, 32, 64);
      if (lane < 16) atomicAdd(&rgbacc[(size_t)(bg * 3 + c) * 4096 + p], t);
    }
  }
}

// ---- finalize rgb: out[b,c,p] = up2(rgb) + rgbB[c] + rgbacc[b,c,p]
__global__ void rgbfin_kernel(const float* __restrict__ rgbacc, const void* __restrict__ rgbB,
                              const void* __restrict__ rgb, void* __restrict__ outb,
                              const int* __restrict__ flag) {
  const int bf = flag[0];
  const int g = blockIdx.x * 256 + threadIdx.x;  // 0..32767
  const int b = g >> 12, p = g & 4095;
  const int oy = p >> 6, ox = p & 63;
  const int m = oy >> 1; int iy0, iy1; float wy0, wy1;
  if ((oy & 1) == 0) { iy0 = (m > 0) ? m - 1 : 0; iy1 = m; wy0 = 0.25f; wy1 = 0.75f; }
  else               { iy0 = m; iy1 = (m < 31) ? m + 1 : 31; wy0 = 0.75f; wy1 = 0.25f; }
  const int mx = ox >> 1; int ix0, ix1; float wx0, wx1;
  if ((ox & 1) == 0) { ix0 = (mx > 0) ? mx - 1 : 0; ix1 = mx; wx0 = 0.25f; wx1 = 0.75f; }
  else               { ix0 = mx; ix1 = (mx < 31) ? mx + 1 : 31; wx0 = 0.75f; wx1 = 0.25f; }
#pragma unroll
  for (int c = 0; c < 3; ++c) {
    const size_t rb = (size_t)(b * 3 + c) * 1024;
    const float up = wy0 * (wx0 * rin(rgb, rb + iy0 * 32 + ix0, bf) + wx1 * rin(rgb, rb + iy0 * 32 + ix1, bf))
                   + wy1 * (wx0 * rin(rgb, rb + iy1 * 32 + ix0, bf) + wx1 * rin(rgb, rb + iy1 * 32 + ix1, bf));
    const float v = up + rin(rgbB, c, bf) + rgbacc[(size_t)(b * 3 + c) * 4096 + p];
    const size_t oi = ((size_t)(b * 3 + c) << 12) + p;
    if (bf) ((u16*)outb)[oi] = f2b(v); else ((float*)outb)[oi] = v;
  }
}

// ---------------- workspace layout (bytes) ----------------
// flag:0(64)  s0:1024  s1:17408  sR:33792  dm0:50176  dm1:66560
// zbuf:82944 (4096, zeroed)  rgbacc:87040 (393216)  -> 480256
// Wp0:480256 (4718592)  Wp1:5198848 (4718592)
// actB:9917440 (NB=8: 35684352 -> end 45.6MB; NB=4 fallback: 17842176 -> end 27.8MB)

extern "C" void kernel_launch(void* const* d_in, const int* in_sizes, int n_in,
                              void* d_out, int out_size, void* d_ws, size_t ws_size,
                              hipStream_t stream) {
  const void* maps   = d_in[0];
  const void* wlat   = d_in[1];
  const void* rgb    = d_in[2];
  const void* noise0 = d_in[3];
  const void* noise1 = d_in[4];
  const void* w0     = d_in[5];
  const void* b0     = d_in[6];
  const void* sW0    = d_in[7];
  const void* sB0    = d_in[8];
  const void* ns0    = d_in[9];
  const void* w1     = d_in[10];
  const void* b1     = d_in[11];
  const void* sW1    = d_in[12];
  const void* sB1    = d_in[13];
  const void* ns1    = d_in[14];
  const void* rgbW   = d_in[15];
  const void* rgbB   = d_in[16];
  const void* rgbSW  = d_in[17];
  const void* rgbSB  = d_in[18];

  char* ws = (char*)d_ws;
  int*   flg    = (int*)(ws + 0);
  float* s0     = (float*)(ws + 1024);
  float* s1     = (float*)(ws + 17408);
  float* sR     = (float*)(ws + 33792);
  float* dm0    = (float*)(ws + 50176);
  float* dm1    = (float*)(ws + 66560);
  u16*   zbuf   = (u16*)(ws + 82944);
  float* rgbacc = (float*)(ws + 87040);
  u16*   Wp0    = (u16*)(ws + 480256);
  u16*   Wp1    = (u16*)(ws + 5198848);
  u16*   actB   = (u16*)(ws + 9917440);

  // full-batch conv launches (4 blocks/CU) if actB for 8 batches fits in ws
  const bool full = ws_size >= (size_t)(9917440 + 35684352);
  const int NB = full ? 8 : 4;

  detect_kernel<<<1, 64, 0, stream>>>((const unsigned*)w0, flg);
  styleall_kernel<<<dim3(8, 8, 3), 256, 0, stream>>>(wlat, sW0, sB0, sW1, sB1, rgbSW, rgbSB,
                                                     s0, s1, sR, flg);
  demod_kernel<<<512, 256, 0, stream>>>(w0, s0, dm0, Wp0, flg);
  demod_kernel<<<512, 256, 0, stream>>>(w1, s1, dm1, Wp1, flg);
  zero_kernel<<<98, 256, 0, stream>>>((u32x4*)zbuf, 24832);          // zbuf + rgbacc
  zero_kernel<<<(NB * 1115136 + 8713) / 256 + 1, 256, 0, stream>>>(  // actB (halo ring stays 0)
      (u32x4*)actB, NB * 278784);

  for (int pass = 0; pass < 8 / NB; ++pass) {
    const int b_base = pass * NB;
    upsample_kernel<<<dim3(64, 16, NB), 256, 0, stream>>>(maps, s0, d_out, b_base, flg);
    conv0_kernel<<<dim3(32, 4, NB), 256, 0, stream>>>(d_out, Wp0, dm0, b0, ns0, noise0, s1,
                                                      actB, zbuf, b_base, flg);
    conv1_kernel<<<dim3(32, 4, NB), 256, 0, stream>>>(actB, Wp1, dm1, b1, ns1, noise1, sR,
                                                      rgbW, rgbacc, d_out, b_base, flg);
  }
  rgbfin_kernel<<<128, 256, 0, stream>>>(rgbacc, rgbB, rgb, d_out, flg);
}

// Round 7
// 504.126 us; speedup vs baseline: 1.9231x; 1.0249x over previous
//
#include <hip/hip_runtime.h>

typedef unsigned short u16;
typedef short bf16x8 __attribute__((ext_vector_type(8)));
typedef float f32x4 __attribute__((ext_vector_type(4)));
typedef u16 u16x4 __attribute__((ext_vector_type(4)));
typedef u16 u16x8 __attribute__((ext_vector_type(8)));
typedef unsigned u32x4 __attribute__((ext_vector_type(4)));

__device__ __forceinline__ float b2f(u16 v) {
  union { unsigned u; float f; } x; x.u = ((unsigned)v) << 16; return x.f;
}
__device__ __forceinline__ u16 f2b(float f) {
  unsigned u = __float_as_uint(f);
  unsigned r = (u + 0x7FFFu + ((u >> 16) & 1u)) >> 16;
  return (u16)r;
}
// dtype-agnostic input read: bf==1 -> bf16, bf==0 -> f32
__device__ __forceinline__ float rin(const void* p, size_t i, int bf) {
  return bf ? b2f(((const u16*)p)[i]) : ((const float*)p)[i];
}
__device__ __forceinline__ void async16(const void* g, void* l) {
  __builtin_amdgcn_global_load_lds((const __attribute__((address_space(1))) unsigned*)g,
                                   (__attribute__((address_space(3))) unsigned*)l, 16, 0, 0);
}
// per-block dtype detection: wave 0 inspects w0's first 64 words (L2-resident),
// broadcasts via LDS. bf16 data -> every low-u16 has plausible small-bf16 exponent.
__device__ __forceinline__ int detect_bf(const unsigned* __restrict__ w0raw, int tid, int* shflag) {
  if (tid < 64) {
    const unsigned lo = w0raw[tid] & 0xFFFFu;
    const unsigned e = (lo >> 7) & 0xFFu;
    const unsigned long long bad = __ballot(e < 100u || e > 126u);
    if (tid == 0) *shflag = (bad == 0ull) ? 1 : 0;
  }
  __syncthreads();
  return *shflag;
}

// ---- all three style GEMMs in one launch: s[b,i] = sum_z w[b,z]*sW[i,z] + sB[i]
__global__ void styleall_kernel(const void* __restrict__ w,
                                const void* __restrict__ sW0, const void* __restrict__ sB0,
                                const void* __restrict__ sW1, const void* __restrict__ sB1,
                                const void* __restrict__ sWR, const void* __restrict__ sBR,
                                float* __restrict__ s0, float* __restrict__ s1,
                                float* __restrict__ sR, const unsigned* __restrict__ w0raw) {
  __shared__ int shflag;
  const int tid = threadIdx.x;
  const int bf = detect_bf(w0raw, tid, &shflag);
  const int mat = blockIdx.z, b = blockIdx.y, oc = blockIdx.x;
  const void* sW = (mat == 0) ? sW0 : ((mat == 1) ? sW1 : sWR);
  const void* sB = (mat == 0) ? sB0 : ((mat == 1) ? sB1 : sBR);
  float* out = (mat == 0) ? s0 : ((mat == 1) ? s1 : sR);
  const int i = oc * 64 + (tid >> 2), q = tid & 3;
  float acc = 0.f;
  if (bf) {
    const u16* rp = (const u16*)sW + (size_t)i * 512 + q * 128;
    const u16* wp = (const u16*)w + b * 512 + q * 128;
    for (int z = 0; z < 128; z += 8) {
      u16x8 a = *(const u16x8*)(rp + z), c = *(const u16x8*)(wp + z);
#pragma unroll
      for (int j = 0; j < 8; ++j) acc += b2f(a[j]) * b2f(c[j]);
    }
  } else {
    const float* rp = (const float*)sW + (size_t)i * 512 + q * 128;
    const float* wp = (const float*)w + b * 512 + q * 128;
    for (int z = 0; z < 128; z += 4) {
      f32x4 a = *(const f32x4*)(rp + z), c = *(const f32x4*)(wp + z);
#pragma unroll
      for (int j = 0; j < 4; ++j) acc += a[j] * c[j];
    }
  }
  acc += __shfl_xor(acc, 1, 64);
  acc += __shfl_xor(acc, 2, 64);
  if (q == 0) out[b * 512 + i] = acc + rin(sB, i, bf);
}

// ---- demod (both layers in one launch, coalesced): block (o, layer).
// Stage W[o] (4608 elems) into LDS with vector loads, then
// wsq[i] = sum_t W[o,i,t]^2 ; repack Wp[t][o][i] ; d[b,o] = rsqrt(sum_i wsq*s^2 + eps)
__global__ void demod_kernel(const void* __restrict__ W0, const void* __restrict__ W1,
                             const float* __restrict__ s0, const float* __restrict__ s1,
                             float* __restrict__ dm0, float* __restrict__ dm1,
                             u16* __restrict__ Wp0, u16* __restrict__ Wp1,
                             const unsigned* __restrict__ w0raw) {
  __shared__ int shflag;
  __shared__ float wl[4608];
  __shared__ float wsq[512];
  const int tid = threadIdx.x, lane = tid & 63, wv = tid >> 6;
  const int bf = detect_bf(w0raw, tid, &shflag);
  const int o = blockIdx.x, layer = blockIdx.y;
  const void* W = layer ? W1 : W0;
  const float* s = layer ? s1 : s0;
  float* d = layer ? dm1 : dm0;
  u16* Wp = layer ? Wp1 : Wp0;

  if (bf) {
    const u16* src = (const u16*)W + (size_t)o * 4608;
    for (int e = tid; e < 576; e += 256) {
      u16x8 v = *(const u16x8*)(src + e * 8);
#pragma unroll
      for (int j = 0; j < 8; ++j) wl[e * 8 + j] = b2f(v[j]);
    }
  } else {
    const float* src = (const float*)W + (size_t)o * 4608;
    for (int e = tid; e < 1152; e += 256) {
      f32x4 v = *(const f32x4*)(src + e * 4);
#pragma unroll
      for (int j = 0; j < 4; ++j) wl[e * 4 + j] = v[j];
    }
  }
  __syncthreads();
  for (int i = tid; i < 512; i += 256) {
    float ss = 0.f;
#pragma unroll
    for (int t = 0; t < 9; ++t) {
      const float f = wl[i * 9 + t];
      ss += f * f;
      Wp[t * 262144 + o * 512 + i] = f2b(f);
    }
    wsq[i] = ss;
  }
  __syncthreads();
#pragma unroll
  for (int bb = 0; bb < 2; ++bb) {
    const int b = wv * 2 + bb;
    float part = 0.f;
    for (int i = lane; i < 512; i += 64) { const float sv = s[b * 512 + i]; part += wsq[i] * sv * sv; }
#pragma unroll
    for (int st = 1; st < 64; st <<= 1) part += __shfl_xor(part, st, 64);
    if (lane == 0) d[b * 512 + o] = rsqrtf(part + 1e-8f);
  }
}

// ---- prep: zero actB's halo ring only (interior is overwritten by conv0) + zbuf/rgbacc
__global__ void prep_kernel(u16* __restrict__ actB, u32x4* __restrict__ zr, int NB) {
  const int id = blockIdx.x, tid = threadIdx.x;
  if (id < NB * 65) {
    const int bl = id / 65, sub = id - bl * 65;
    const int c = sub * 256 + tid;      // 0..16639 : 260 ring px x 64 chunks
    const int px = c >> 6, seg = c & 63;
    int oy, ox;
    if (px < 66)       { oy = 0;  ox = px; }
    else if (px < 132) { oy = 65; ox = px - 66; }
    else { const int e = px - 132; oy = 1 + (e >> 1); ox = (e & 1) * 65; }
    u32x4 z = {0, 0, 0, 0};
    *(u32x4*)&actB[((size_t)(bl * 4356) + oy * 66 + ox) * 512 + seg * 8] = z;
  } else {
    const int c = (id - NB * 65) * 256 + tid;
    if (c < 24832) { u32x4 z = {0, 0, 0, 0}; zr[c] = z; }
  }
}

// ---- bilinear 2x upsample * s0 -> bf16 NHWC scratch [bl][4096][512] inside d_out x-region
__global__ void upsample_kernel(const void* __restrict__ maps, const float* __restrict__ s,
                                void* __restrict__ outb, int b_base,
                                const unsigned* __restrict__ w0raw) {
  __shared__ int shflag;
  __shared__ float it[32][2][33];
  const int tid = threadIdx.x;
  const int bf = detect_bf(w0raw, tid, &shflag);
  const size_t esz = bf ? 2 : 4;
  u16* xg = (u16*)((char*)outb + (98304 + (size_t)(b_base >> 2) * 8388608) * esz);
  const int oy = blockIdx.x;       // 0..63
  const int i0 = blockIdx.y * 32;  // channel chunk
  const int bl = blockIdx.z;       // local batch
  const int bg = b_base + bl;
  const int m = oy >> 1;
  int iy0, iy1; float wy0, wy1;
  if ((oy & 1) == 0) { iy0 = (m > 0) ? m - 1 : 0; iy1 = m; wy0 = 0.25f; wy1 = 0.75f; }
  else               { iy0 = m; iy1 = (m < 31) ? m + 1 : 31; wy0 = 0.75f; wy1 = 0.25f; }
#pragma unroll
  for (int k = 0; k < 8; ++k) {
    const int e = tid + k * 256;  // 32c x 2rows x 32x = 2048
    const int c = e >> 6, wsel = (e >> 5) & 1, x = e & 31;
    const int iy = wsel ? iy1 : iy0;
    it[c][wsel][x] = rin(maps, ((size_t)(bg * 512 + i0 + c) * 32 + iy) * 32 + x, bf);
  }
  __syncthreads();
#pragma unroll
  for (int k = 0; k < 8; ++k) {
    const int e = tid + k * 256;  // 64 xx * 32 c = 2048
    const int xx = e >> 5, c = e & 31;
    const int mx = xx >> 1;
    int ix0, ix1; float wx0, wx1;
    if ((xx & 1) == 0) { ix0 = (mx > 0) ? mx - 1 : 0; ix1 = mx; wx0 = 0.25f; wx1 = 0.75f; }
    else               { ix0 = mx; ix1 = (mx < 31) ? mx + 1 : 31; wx0 = 0.75f; wx1 = 0.25f; }
    const float r0 = wx0 * it[c][0][ix0] + wx1 * it[c][0][ix1];
    const float r1 = wx0 * it[c][1][ix0] + wx1 * it[c][1][ix1];
    const float v = (wy0 * r0 + wy1 * r1) * s[bg * 512 + i0 + c];
    xg[((size_t)(bl * 4096) + oy * 64 + xx) * 512 + i0 + c] = f2b(v);
  }
}

// ---- conv0: implicit GEMM 3x3, BK=64; boundary staging lanes redirect to zeroed zbuf.
// epilogue: lrelu(acc*dm + b + ns*noise)*s1 -> actB halo NHWC [bl][66][66][512]
__global__ __launch_bounds__(256) void conv0_kernel(
    const void* __restrict__ outb, const u16* __restrict__ Wp,
    const float* __restrict__ dmod, const void* __restrict__ bias,
    const void* __restrict__ nsc, const void* __restrict__ noise,
    const float* __restrict__ snext, u16* __restrict__ actB,
    const u16* __restrict__ zbuf, int b_base, const unsigned* __restrict__ w0raw) {
  __shared__ __attribute__((aligned(16))) u16 Alds[8192];
  __shared__ __attribute__((aligned(16))) u16 Blds[8192];
  __shared__ int shflag;
  const int tid = threadIdx.x, lane = tid & 63, w = tid >> 6;
  const int bf = detect_bf(w0raw, tid, &shflag);
  const size_t esz = bf ? 2 : 4;
  const u16* xg = (const u16*)((const char*)outb + (98304 + (size_t)(b_base >> 2) * 8388608) * esz);
  const int wm = w >> 1, wn = w & 1;
  const int n0 = blockIdx.x * 128, o0 = blockIdx.y * 128;
  const int bl = blockIdx.z, bg = b_base + bl;

  const int srow = w * 32 + (lane >> 2);
  const int scol = (lane & 3) * 8;
  const size_t aA = (size_t)(o0 + srow) * 512 + scol;
  const int p0 = n0 + srow, p1 = p0 + 16;
  const int oy0 = p0 >> 6, ox0 = p0 & 63;
  const int oy1 = p1 >> 6, ox1 = p1 & 63;
  u16* lA0 = &Alds[w * 1024]; u16* lA1 = &Alds[w * 1024 + 512];
  u16* lB0 = &Blds[w * 1024]; u16* lB1 = &Blds[w * 1024 + 512];

  f32x4 acc[4][4] = {};
  const int q = lane >> 4, mrow = lane & 15;

#pragma unroll 1
  for (int t = 0; t < 9; ++t) {
    const int ty = t / 3, tx = t % 3;
    const size_t wbase = (size_t)t * 262144;
    const int iy0 = oy0 + ty - 1, ix0 = ox0 + tx - 1;
    const int iy1 = oy1 + ty - 1, ix1 = ox1 + tx - 1;
    const bool ok0 = ((unsigned)iy0 < 64u) && ((unsigned)ix0 < 64u);
    const bool ok1 = ((unsigned)iy1 < 64u) && ((unsigned)ix1 < 64u);
    const u16* baseB0 = ok0 ? (xg + (((size_t)(bl * 4096) + iy0 * 64 + ix0) * 512 + scol)) : (zbuf + scol);
    const u16* baseB1 = ok1 ? (xg + (((size_t)(bl * 4096) + iy1 * 64 + ix1) * 512 + scol)) : (zbuf + scol);
    const u16* baseA = Wp + wbase + aA;
#pragma unroll 1
    for (int kc = 0; kc < 8; ++kc) {
      const int ko = kc * 64;
      __syncthreads();                 // prior iteration's LDS reads complete
      async16(baseA + ko, lA0);
      async16(baseA + ko + 16 * 512, lA1);
      async16(baseA + ko + 32, lA0 + 4096);
      async16(baseA + ko + 32 + 16 * 512, lA1 + 4096);
      async16(baseB0 + ko, lB0);
      async16(baseB1 + ko, lB1);
      async16(baseB0 + ko + 32, lB0 + 4096);
      async16(baseB1 + ko + 32, lB1 + 4096);
      __syncthreads();                 // vmcnt-drained barrier: staging visible
#pragma unroll
      for (int kk = 0; kk < 2; ++kk) {
        bf16x8 af[4], bfv[4];
#pragma unroll
        for (int mi = 0; mi < 4; ++mi)
          af[mi] = *(const bf16x8*)&Alds[kk * 4096 + (wm * 64 + mi * 16 + mrow) * 32 + q * 8];
#pragma unroll
        for (int ni = 0; ni < 4; ++ni)
          bfv[ni] = *(const bf16x8*)&Blds[kk * 4096 + (wn * 64 + ni * 16 + mrow) * 32 + q * 8];
#pragma unroll
        for (int mi = 0; mi < 4; ++mi)
#pragma unroll
          for (int ni = 0; ni < 4; ++ni)
            acc[mi][ni] = __builtin_amdgcn_mfma_f32_16x16x32_bf16(af[mi], bfv[ni], acc[mi][ni], 0, 0, 0);
      }
    }
  }

#pragma unroll
  for (int mi = 0; mi < 4; ++mi) {
    const int o = o0 + wm * 64 + mi * 16 + q * 4;
    const f32x4 dv = *(const f32x4*)&dmod[bg * 512 + o];
    const f32x4 sv = *(const f32x4*)&snext[bg * 512 + o];
    float bv[4], nv[4];
#pragma unroll
    for (int r = 0; r < 4; ++r) { bv[r] = rin(bias, o + r, bf); nv[r] = rin(nsc, o + r, bf); }
#pragma unroll
    for (int ni = 0; ni < 4; ++ni) {
      const int p = n0 + wn * 64 + ni * 16 + mrow;
      const float np = rin(noise, (size_t)bg * 4096 + p, bf);
      u16x4 pack;
#pragma unroll
      for (int r = 0; r < 4; ++r) {
        float v = acc[mi][ni][r] * dv[r] + bv[r] + nv[r] * np;
        v = (v >= 0.f) ? v : 0.2f * v;
        pack[r] = f2b(v * sv[r]);
      }
      const int oy = p >> 6, ox = p & 63;
      *(u16x4*)&actB[((size_t)(bl * 4356) + (oy + 1) * 66 + (ox + 1)) * 512 + o] = pack;
    }
  }
}

// ---- conv1: implicit GEMM 3x3 over halo NHWC actB, BK=64.
// epilogue: x = lrelu(acc*dm + b + ns*noise) -> d_out x-region (dual dtype, NCHW);
//           rgb partials: atomicAdd rgbacc[b][c][p] += sum_o rgbW[c][o]*(x*sR)[o]
__global__ __launch_bounds__(256) void conv1_kernel(
    const u16* __restrict__ actB, const u16* __restrict__ Wp,
    const float* __restrict__ dmod, const void* __restrict__ bias,
    const void* __restrict__ nsc, const void* __restrict__ noise,
    const float* __restrict__ sR, const void* __restrict__ rgbW,
    float* __restrict__ rgbacc, void* __restrict__ outb, int b_base,
    const unsigned* __restrict__ w0raw) {
  __shared__ __attribute__((aligned(16))) u16 Alds[8192];
  __shared__ __attribute__((aligned(16))) u16 Blds[8192];
  __shared__ float rgbWl[1536];
  __shared__ int shflag;
  const int tid = threadIdx.x, lane = tid & 63, w = tid >> 6;
  const int bf = detect_bf(w0raw, tid, &shflag);
  const int wm = w >> 1, wn = w & 1;
  const int n0 = blockIdx.x * 128, o0 = blockIdx.y * 128;
  const int bl = blockIdx.z, bg = b_base + bl;

  for (int e = tid; e < 1536; e += 256) rgbWl[e] = rin(rgbW, e, bf);

  const int srow = w * 32 + (lane >> 2);
  const int scol = (lane & 3) * 8;
  const size_t aA = (size_t)(o0 + srow) * 512 + scol;
  const int p0 = n0 + srow, p1 = p0 + 16;
  const size_t aB0 = ((size_t)(bl * 4356) + (p0 >> 6) * 66 + (p0 & 63)) * 512 + scol;
  const size_t aB1 = ((size_t)(bl * 4356) + (p1 >> 6) * 66 + (p1 & 63)) * 512 + scol;
  u16* lA0 = &Alds[w * 1024]; u16* lA1 = &Alds[w * 1024 + 512];
  u16* lB0 = &Blds[w * 1024]; u16* lB1 = &Blds[w * 1024 + 512];

  f32x4 acc[4][4] = {};
  const int q = lane >> 4, mrow = lane & 15;

#pragma unroll 1
  for (int t = 0; t < 9; ++t) {
    const int toffB = ((t / 3) * 66 + (t % 3)) * 512;
    const u16* baseA = Wp + (size_t)t * 262144 + aA;
    const u16* baseB0 = actB + aB0 + toffB;
    const u16* baseB1 = actB + aB1 + toffB;
#pragma unroll 1
    for (int kc = 0; kc < 8; ++kc) {
      const int ko = kc * 64;
      __syncthreads();
      async16(baseA + ko, lA0);
      async16(baseA + ko + 16 * 512, lA1);
      async16(baseA + ko + 32, lA0 + 4096);
      async16(baseA + ko + 32 + 16 * 512, lA1 + 4096);
      async16(baseB0 + ko, lB0);
      async16(baseB1 + ko, lB1);
      async16(baseB0 + ko + 32, lB0 + 4096);
      async16(baseB1 + ko + 32, lB1 + 4096);
      __syncthreads();
#pragma unroll
      for (int kk = 0; kk < 2; ++kk) {
        bf16x8 af[4], bfv[4];
#pragma unroll
        for (int mi = 0; mi < 4; ++mi)
          af[mi] = *(const bf16x8*)&Alds[kk * 4096 + (wm * 64 + mi * 16 + mrow) * 32 + q * 8];
#pragma unroll
        for (int ni = 0; ni < 4; ++ni)
          bfv[ni] = *(const bf16x8*)&Blds[kk * 4096 + (wn * 64 + ni * 16 + mrow) * 32 + q * 8];
#pragma unroll
        for (int mi = 0; mi < 4; ++mi)
#pragma unroll
          for (int ni = 0; ni < 4; ++ni)
            acc[mi][ni] = __builtin_amdgcn_mfma_f32_16x16x32_bf16(af[mi], bfv[ni], acc[mi][ni], 0, 0, 0);
      }
    }
  }

  const size_t esz = bf ? 2 : 4;
  char* xreg = (char*)outb + 98304 * esz;
  float racc[4][3] = {};
#pragma unroll
  for (int mi = 0; mi < 4; ++mi) {
    const int o = o0 + wm * 64 + mi * 16 + q * 4;
    const f32x4 dv = *(const f32x4*)&dmod[bg * 512 + o];
    const f32x4 srv = *(const f32x4*)&sR[bg * 512 + o];
    float bv[4], nv[4], w0l[4], w1l[4], w2l[4];
#pragma unroll
    for (int r = 0; r < 4; ++r) {
      bv[r] = rin(bias, o + r, bf); nv[r] = rin(nsc, o + r, bf);
      w0l[r] = rgbWl[o + r]; w1l[r] = rgbWl[512 + o + r]; w2l[r] = rgbWl[1024 + o + r];
    }
#pragma unroll
    for (int ni = 0; ni < 4; ++ni) {
      const int p = n0 + wn * 64 + ni * 16 + mrow;
      const float np = rin(noise, (size_t)bg * 4096 + p, bf);
#pragma unroll
      for (int r = 0; r < 4; ++r) {
        float v = acc[mi][ni][r] * dv[r] + bv[r] + nv[r] * np;
        v = (v >= 0.f) ? v : 0.2f * v;
        const size_t xi = (size_t)(bg * 512 + o + r) * 4096 + p;
        if (bf) ((u16*)xreg)[xi] = f2b(v); else ((float*)xreg)[xi] = v;
        const float xr = v * srv[r];
        racc[ni][0] += w0l[r] * xr;
        racc[ni][1] += w1l[r] * xr;
        racc[ni][2] += w2l[r] * xr;
      }
    }
  }
#pragma unroll
  for (int ni = 0; ni < 4; ++ni) {
    const int p = n0 + wn * 64 + ni * 16 + mrow;
#pragma unroll
    for (int c = 0; c < 3; ++c) {
      float t = racc[ni][c];
      t += __shfl_xor(t, 16, 64);
      t += __shfl_xor(t, 32, 64);
      if (lane < 16) atomicAdd(&rgbacc[(size_t)(bg * 3 + c) * 4096 + p], t);
    }
  }
}

// ---- finalize rgb: out[b,c,p] = up2(rgb) + rgbB[c] + rgbacc[b,c,p]
__global__ void rgbfin_kernel(const float* __restrict__ rgbacc, const void* __restrict__ rgbB,
                              const void* __restrict__ rgb, void* __restrict__ outb,
                              const unsigned* __restrict__ w0raw) {
  __shared__ int shflag;
  const int tid = threadIdx.x;
  const int bf = detect_bf(w0raw, tid, &shflag);
  const int g = blockIdx.x * 256 + tid;  // 0..32767
  const int b = g >> 12, p = g & 4095;
  const int oy = p >> 6, ox = p & 63;
  const int m = oy >> 1; int iy0, iy1; float wy0, wy1;
  if ((oy & 1) == 0) { iy0 = (m > 0) ? m - 1 : 0; iy1 = m; wy0 = 0.25f; wy1 = 0.75f; }
  else               { iy0 = m; iy1 = (m < 31) ? m + 1 : 31; wy0 = 0.75f; wy1 = 0.25f; }
  const int mx = ox >> 1; int ix0, ix1; float wx0, wx1;
  if ((ox & 1) == 0) { ix0 = (mx > 0) ? mx - 1 : 0; ix1 = mx; wx0 = 0.25f; wx1 = 0.75f; }
  else               { ix0 = mx; ix1 = (mx < 31) ? mx + 1 : 31; wx0 = 0.75f; wx1 = 0.25f; }
#pragma unroll
  for (int c = 0; c < 3; ++c) {
    const size_t rb = (size_t)(b * 3 + c) * 1024;
    const float up = wy0 * (wx0 * rin(rgb, rb + iy0 * 32 + ix0, bf) + wx1 * rin(rgb, rb + iy0 * 32 + ix1, bf))
                   + wy1 * (wx0 * rin(rgb, rb + iy1 * 32 + ix0, bf) + wx1 * rin(rgb, rb + iy1 * 32 + ix1, bf));
    const float v = up + rin(rgbB, c, bf) + rgbacc[(size_t)(b * 3 + c) * 4096 + p];
    const size_t oi = ((size_t)(b * 3 + c) << 12) + p;
    if (bf) ((u16*)outb)[oi] = f2b(v); else ((float*)outb)[oi] = v;
  }
}

// ---------------- workspace layout (bytes) ----------------
// s0:1024  s1:17408  sR:33792  dm0:50176  dm1:66560
// zbuf:82944 (4096, zeroed)  rgbacc:87040 (393216)  -> 480256
// Wp0:480256 (4718592)  Wp1:5198848 (4718592)
// actB:9917440 (NB=8: 35684352 -> end 45.6MB; NB=4 fallback -> 27.8MB)

extern "C" void kernel_launch(void* const* d_in, const int* in_sizes, int n_in,
                              void* d_out, int out_size, void* d_ws, size_t ws_size,
                              hipStream_t stream) {
  const void* maps   = d_in[0];
  const void* wlat   = d_in[1];
  const void* rgb    = d_in[2];
  const void* noise0 = d_in[3];
  const void* noise1 = d_in[4];
  const void* w0     = d_in[5];
  const void* b0     = d_in[6];
  const void* sW0    = d_in[7];
  const void* sB0    = d_in[8];
  const void* ns0    = d_in[9];
  const void* w1     = d_in[10];
  const void* b1     = d_in[11];
  const void* sW1    = d_in[12];
  const void* sB1    = d_in[13];
  const void* ns1    = d_in[14];
  const void* rgbW   = d_in[15];
  const void* rgbB   = d_in[16];
  const void* rgbSW  = d_in[17];
  const void* rgbSB  = d_in[18];
  const unsigned* w0raw = (const unsigned*)w0;

  char* ws = (char*)d_ws;
  float* s0     = (float*)(ws + 1024);
  float* s1     = (float*)(ws + 17408);
  float* sR     = (float*)(ws + 33792);
  float* dm0    = (float*)(ws + 50176);
  float* dm1    = (float*)(ws + 66560);
  u16*   zbuf   = (u16*)(ws + 82944);
  float* rgbacc = (float*)(ws + 87040);
  u16*   Wp0    = (u16*)(ws + 480256);
  u16*   Wp1    = (u16*)(ws + 5198848);
  u16*   actB   = (u16*)(ws + 9917440);

  // full-batch conv launches (best occupancy) if actB for 8 batches fits in ws
  const bool full = ws_size >= (size_t)(9917440 + 35684352);
  const int NB = full ? 8 : 4;

  styleall_kernel<<<dim3(8, 8, 3), 256, 0, stream>>>(wlat, sW0, sB0, sW1, sB1, rgbSW, rgbSB,
                                                     s0, s1, sR, w0raw);
  demod_kernel<<<dim3(512, 2), 256, 0, stream>>>(w0, w1, s0, s1, dm0, dm1, Wp0, Wp1, w0raw);
  prep_kernel<<<NB * 65 + 97, 256, 0, stream>>>(actB, (u32x4*)zbuf, NB);

  for (int pass = 0; pass < 8 / NB; ++pass) {
    const int b_base = pass * NB;
    upsample_kernel<<<dim3(64, 16, NB), 256, 0, stream>>>(maps, s0, d_out, b_base, w0raw);
    conv0_kernel<<<dim3(32, 4, NB), 256, 0, stream>>>(d_out, Wp0, dm0, b0, ns0, noise0, s1,
                                                      actB, zbuf, b_base, w0raw);
    conv1_kernel<<<dim3(32, 4, NB), 256, 0, stream>>>(actB, Wp1, dm1, b1, ns1, noise1, sR,
                                                      rgbW, rgbacc, d_out, b_base, w0raw);
  }
  rgbfin_kernel<<<128, 256, 0, stream>>>(rgbacc, rgbB, rgb, d_out, w0raw);
}